// Round 4
// baseline (432.381 us; speedup 1.0000x reference)
//
#include <hip/hip_runtime.h>

// ---- problem constants ----
static constexpr int kN = 64;    // nodes
static constexpr int kD = 1024;  // feature dim
static constexpr int kE = 1024;  // edges (16 per row, row-major by (i,j))
static constexpr int kT = 2;     // iterations

typedef short  bf16x8 __attribute__((ext_vector_type(8)));
typedef float  f32x4  __attribute__((ext_vector_type(4)));
typedef unsigned short us8 __attribute__((ext_vector_type(8)));
typedef unsigned short us4 __attribute__((ext_vector_type(4)));

__device__ __forceinline__ unsigned short f2b(float f) {
    unsigned int u = __builtin_bit_cast(unsigned int, f);
    u += 0x7FFFu + ((u >> 16) & 1u);          // RNE
    return (unsigned short)(u >> 16);
}
__device__ __forceinline__ bf16x8 cvt8(float4 a, float4 b) {
    us8 o;
    o[0] = f2b(a.x); o[1] = f2b(a.y); o[2] = f2b(a.z); o[3] = f2b(a.w);
    o[4] = f2b(b.x); o[5] = f2b(b.y); o[6] = f2b(b.z); o[7] = f2b(b.w);
    return __builtin_bit_cast(bf16x8, o);
}
__device__ __forceinline__ float4 mul4(float4 a, float4 b) {
    return make_float4(a.x * b.x, a.y * b.y, a.z * b.z, a.w * b.w);
}
__device__ __forceinline__ float4 sub4(float4 a, float4 b) {
    return make_float4(a.x - b.x, a.y - b.y, a.z - b.z, a.w - b.w);
}

// A-operand source: mode 0 = bf16 direct (row stride 1024, K<=1024);
// mode 1 = concat of f32 segments f0|f1|f2 (each [rows][1024]);
// mode 2 = joint(x=f0, c=f1): [x, c, x*c, dsign ? c-x : x-c]
struct ASrc {
    const unsigned short* bf;
    const float* f0; const float* f1; const float* f2;
    int mode; int dsign;
};

__device__ __forceinline__ bf16x8 loadA8(const ASrc& s, int row, int kg) {
    if (s.mode == 0)
        return *(const bf16x8*)(s.bf + (size_t)row * 1024 + kg);
    const int seg = kg >> 10, k = kg & 1023;
    const size_t ro = (size_t)row * 1024 + k;
    if (s.mode == 1) {
        const float* p = (seg == 0) ? s.f0 : (seg == 1 ? s.f1 : s.f2);
        return cvt8(*(const float4*)(p + ro), *(const float4*)(p + ro + 4));
    }
    // joint
    float4 x0, x1, c0, c1;
    if (seg != 1) { x0 = *(const float4*)(s.f0 + ro); x1 = *(const float4*)(s.f0 + ro + 4); }
    if (seg != 0) { c0 = *(const float4*)(s.f1 + ro); c1 = *(const float4*)(s.f1 + ro + 4); }
    if (seg == 0) return cvt8(x0, x1);
    if (seg == 1) return cvt8(c0, c1);
    if (seg == 2) return cvt8(mul4(x0, c0), mul4(x1, c1));
    return s.dsign ? cvt8(sub4(c0, x0), sub4(c1, x1))
                   : cvt8(sub4(x0, c0), sub4(x1, c1));
}

// =====================================================================
// 128x128-tile MFMA GEMM (M=1024, O=1024): C = A @ W^T, f32 partials
// part[kz][1024*1024]. 256 thr = 4 waves, each 64x64 out. BK=64.
// LDS [128][64] bf16 with 16B-chunk XOR swizzle (c8 ^ row&7).
// =====================================================================
__global__ __launch_bounds__(256)
void k_gemm128(ASrc As_, const unsigned short* __restrict__ W, int ldw,
               float* __restrict__ part, int K, int KS)
{
    __shared__ unsigned short As[128][64];
    __shared__ unsigned short Bs[128][64];
    const int tid = threadIdx.x, lane = tid & 63, wid = tid >> 6;
    const int rowBase = blockIdx.y * 128, colBase = blockIdx.x * 128;
    const int kz = blockIdx.z;
    const int kchunk = K / KS, kbeg = kz * kchunk, kend = kbeg + kchunk;
    const int sr = tid >> 3, sc8 = tid & 7;

    bf16x8 ra[4], rb[4];
    auto stage = [&](int kt) {
#pragma unroll
        for (int h = 0; h < 4; ++h) {
            ra[h] = loadA8(As_, rowBase + sr + 32 * h, kt + sc8 * 8);
            rb[h] = *(const bf16x8*)(W + (size_t)(colBase + sr + 32 * h) * ldw + kt + sc8 * 8);
        }
    };

    f32x4 acc[4][4] = {};
    const int wr = wid >> 1, wc = wid & 1;
    const int l15 = lane & 15, l4 = lane >> 4;

    stage(kbeg);
    for (int kt = kbeg; kt < kend; kt += 64) {
        __syncthreads();
#pragma unroll
        for (int h = 0; h < 4; ++h) {
            const int row = sr + 32 * h;
            const int wc8 = (sc8 ^ (row & 7)) * 8;
            *(bf16x8*)&As[row][wc8] = ra[h];
            *(bf16x8*)&Bs[row][wc8] = rb[h];
        }
        __syncthreads();
        if (kt + 64 < kend) stage(kt + 64);
#pragma unroll
        for (int kk = 0; kk < 2; ++kk) {
            bf16x8 af[4], bv[4];
#pragma unroll
            for (int m = 0; m < 4; ++m) {
                const int ar = wr * 64 + m * 16 + l15;
                af[m] = *(const bf16x8*)&As[ar][(((kk << 2) | l4) ^ (ar & 7)) * 8];
            }
#pragma unroll
            for (int n = 0; n < 4; ++n) {
                const int br = wc * 64 + n * 16 + l15;
                bv[n] = *(const bf16x8*)&Bs[br][(((kk << 2) | l4) ^ (br & 7)) * 8];
            }
#pragma unroll
            for (int m = 0; m < 4; ++m)
#pragma unroll
                for (int n = 0; n < 4; ++n)
                    acc[m][n] = __builtin_amdgcn_mfma_f32_16x16x32_bf16(af[m], bv[n], acc[m][n], 0, 0, 0);
        }
    }
    float* base = part + (size_t)kz * (1024 * 1024);
#pragma unroll
    for (int m = 0; m < 4; ++m) {
        const int row = rowBase + wr * 64 + m * 16 + l4 * 4;
#pragma unroll
        for (int n = 0; n < 4; ++n) {
            const int col = colBase + wc * 64 + n * 16 + l15;
#pragma unroll
            for (int r = 0; r < 4; ++r)
                base[(size_t)(row + r) * 1024 + col] = acc[m][n][r];
        }
    }
}

// =====================================================================
// skinny GEMM (M=64, O=1024), batched over nb weight sets.
// grid (16, 1, nb*KS); b = z%nb, kz = z/nb; part[(kz*nb+b)][64*1024].
// 64x64 tile, 4 waves each 32x32.
// =====================================================================
struct SkinnyW { const unsigned short* W[4]; int ldw[4]; };

__global__ __launch_bounds__(256)
void k_gemm64(ASrc As_, SkinnyW Ws, float* __restrict__ part, int K, int KS, int nb)
{
    __shared__ unsigned short As[64][64];
    __shared__ unsigned short Bs[64][64];
    const int tid = threadIdx.x, lane = tid & 63, wid = tid >> 6;
    const int colBase = blockIdx.x * 64;
    const int b = blockIdx.z % nb, kz = blockIdx.z / nb;
    const unsigned short* __restrict__ W = Ws.W[b];
    const int ldw = Ws.ldw[b];
    const int kchunk = K / KS, kbeg = kz * kchunk, kend = kbeg + kchunk;
    const int sr = tid >> 3, sc8 = tid & 7;

    bf16x8 ra[2], rb[2];
    auto stage = [&](int kt) {
#pragma unroll
        for (int h = 0; h < 2; ++h) {
            ra[h] = loadA8(As_, sr + 32 * h, kt + sc8 * 8);
            rb[h] = *(const bf16x8*)(W + (size_t)(colBase + sr + 32 * h) * ldw + kt + sc8 * 8);
        }
    };

    f32x4 acc[2][2] = {};
    const int wr = wid >> 1, wc = wid & 1;
    const int l15 = lane & 15, l4 = lane >> 4;

    stage(kbeg);
    for (int kt = kbeg; kt < kend; kt += 64) {
        __syncthreads();
#pragma unroll
        for (int h = 0; h < 2; ++h) {
            const int row = sr + 32 * h;
            const int wc8 = (sc8 ^ (row & 7)) * 8;
            *(bf16x8*)&As[row][wc8] = ra[h];
            *(bf16x8*)&Bs[row][wc8] = rb[h];
        }
        __syncthreads();
        if (kt + 64 < kend) stage(kt + 64);
#pragma unroll
        for (int kk = 0; kk < 2; ++kk) {
            bf16x8 af[2], bv[2];
#pragma unroll
            for (int m = 0; m < 2; ++m) {
                const int ar = wr * 32 + m * 16 + l15;
                af[m] = *(const bf16x8*)&As[ar][(((kk << 2) | l4) ^ (ar & 7)) * 8];
            }
#pragma unroll
            for (int n = 0; n < 2; ++n) {
                const int br = wc * 32 + n * 16 + l15;
                bv[n] = *(const bf16x8*)&Bs[br][(((kk << 2) | l4) ^ (br & 7)) * 8];
            }
#pragma unroll
            for (int m = 0; m < 2; ++m)
#pragma unroll
                for (int n = 0; n < 2; ++n)
                    acc[m][n] = __builtin_amdgcn_mfma_f32_16x16x32_bf16(af[m], bv[n], acc[m][n], 0, 0, 0);
        }
    }
    float* base = part + ((size_t)kz * nb + b) * (64 * 1024);
#pragma unroll
    for (int m = 0; m < 2; ++m) {
        const int row = wr * 32 + m * 16 + l4 * 4;
#pragma unroll
        for (int n = 0; n < 2; ++n) {
            const int col = colBase + wc * 32 + n * 16 + l15;
#pragma unroll
            for (int r = 0; r < 4; ++r)
                base[(size_t)(row + r) * 1024 + col] = acc[m][n][r];
        }
    }
}

// =====================================================================
// split-K reduce with fused epilogues.
// out[i] = sum_z P[z][i] (+ bias[col]) (+ a_s[i_e] + a_o[j_e] via edge_idx)
// writes f32 (Cf) and/or bf16 (Cb). O assumed 1024 when bias/eidx used.
// =====================================================================
__global__ void k_reduce(const float* __restrict__ P, int MO4, int KS,
                         float* __restrict__ Cf, unsigned short* __restrict__ Cb,
                         const float* __restrict__ bias,
                         const int* __restrict__ eidx,
                         const float* __restrict__ as_, const float* __restrict__ ao_)
{
    int i = blockIdx.x * blockDim.x + threadIdx.x;
    if (i >= MO4) return;
    float4 s = make_float4(0.f, 0.f, 0.f, 0.f);
    for (int z = 0; z < KS; ++z) {
        const float4 v = reinterpret_cast<const float4*>(P)[(size_t)z * MO4 + i];
        s.x += v.x; s.y += v.y; s.z += v.z; s.w += v.w;
    }
    if (eidx) {
        const int e = i >> 8, c = i & 255;
        const int idx = eidx[e];
        const float4 u = reinterpret_cast<const float4*>(as_)[(size_t)(idx >> 6) * 256 + c];
        const float4 v = reinterpret_cast<const float4*>(ao_)[(size_t)(idx & 63) * 256 + c];
        s.x += u.x + v.x; s.y += u.y + v.y; s.z += u.z + v.z; s.w += u.w + v.w;
    }
    if (bias) {
        const float4 b = reinterpret_cast<const float4*>(bias)[i & 255];
        s.x += b.x; s.y += b.y; s.z += b.z; s.w += b.w;
    }
    if (Cf) reinterpret_cast<float4*>(Cf)[i] = s;
    if (Cb) {
        us4 o; o.x = f2b(s.x); o.y = f2b(s.y); o.z = f2b(s.z); o.w = f2b(s.w);
        *(us4*)(Cb + (size_t)i * 4) = o;
    }
}

// batched f32 -> bf16 conversion (7 weight matrices), one launch
struct ConvBatch {
    const float* s[7];
    unsigned short* d[7];
    int beg8[7];
    int total8;
};
__global__ void k_f2b_batch(ConvBatch cb)
{
    int i = blockIdx.x * blockDim.x + threadIdx.x;
    if (i >= cb.total8) return;
    int k = 0;
    while (k < 6 && i >= cb.beg8[k + 1]) ++k;
    const int j = i - cb.beg8[k];
    const float4 v0 = reinterpret_cast<const float4*>(cb.s[k])[2 * j];
    const float4 v1 = reinterpret_cast<const float4*>(cb.s[k])[2 * j + 1];
    const bf16x8 o = cvt8(v0, v1);
    *(bf16x8*)(cb.d[k] + (size_t)j * 8) = o;
}

// transpose 4 f32 [1024][1024] matrices into bf16 [1024][1024] (dst[k][o]=src[o][k])
struct T4 { const float* s[4]; unsigned short* d[4]; };
__global__ __launch_bounds__(256)
void k_transpose(T4 t4)
{
    __shared__ float tile[64][65];
    const float* __restrict__ src = t4.s[blockIdx.z];
    unsigned short* __restrict__ dst = t4.d[blockIdx.z];
    const int bx = blockIdx.x * 64, by = blockIdx.y * 64;
    const int c = threadIdx.x & 63, r0 = threadIdx.x >> 6;
#pragma unroll
    for (int h = 0; h < 16; ++h) {
        const int r = r0 * 16 + h;
        tile[r][c] = src[(size_t)(by + r) * 1024 + bx + c];
    }
    __syncthreads();
#pragma unroll
    for (int h = 0; h < 16; ++h) {
        const int kk = r0 * 16 + h;
        dst[(size_t)(bx + kk) * 1024 + by + c] = f2b(tile[c][kk]);
    }
}

// s_sbj[e] = <qW_s[i_e], relj[e]>/32 ; s_obj[e] = <qW_o[j_e], relj[e]>/32
__global__ __launch_bounds__(256)
void k_scores(const float* __restrict__ qws, const float* __restrict__ qwo,
              const float* __restrict__ relj, const int* __restrict__ eidx,
              float* __restrict__ s_sbj, float* __restrict__ s_obj)
{
    const int e = blockIdx.x, t = threadIdx.x;
    const int idx = eidx[e];
    const int i = idx >> 6, j = idx & 63;
    const float4 r = reinterpret_cast<const float4*>(relj)[(size_t)e * 256 + t];
    const float4 a = reinterpret_cast<const float4*>(qws)[(size_t)i * 256 + t];
    const float4 b = reinterpret_cast<const float4*>(qwo)[(size_t)j * 256 + t];
    float vs = a.x * r.x + a.y * r.y + a.z * r.z + a.w * r.w;
    float vo = b.x * r.x + b.y * r.y + b.z * r.z + b.w * r.w;
    for (int off = 32; off; off >>= 1) {
        vs += __shfl_down(vs, off);
        vo += __shfl_down(vo, off);
    }
    __shared__ float ss[4], so[4];
    const int w = t >> 6, lane = t & 63;
    if (lane == 0) { ss[w] = vs; so[w] = vo; }
    __syncthreads();
    if (t == 0) {
        s_sbj[e] = (ss[0] + ss[1] + ss[2] + ss[3]) * 0.03125f;
        s_obj[e] = (so[0] + so[1] + so[2] + so[3]) * 0.03125f;
    }
}

// fused softmax + weighted aggregation.
// block < 64: ctx1[i] = sum_q softmax_row(s_sbj[16i..])_q * relj[16i+q]
// block >= 64: ctx2[j] = sum_i softmax_col(s_obj | conn col j)_i * relj[e]
__global__ __launch_bounds__(256)
void k_ctx12(const float* __restrict__ relj, const float* __restrict__ s_sbj,
             const float* __restrict__ s_obj, const int* __restrict__ conn,
             float* __restrict__ ctx1, float* __restrict__ ctx2)
{
    const int bid = blockIdx.x, t = threadIdx.x;
    const float4* relj4 = reinterpret_cast<const float4*>(relj);
    if (bid < 64) {
        const int i = bid;
        float sv[16];
        float m = -1e30f;
#pragma unroll
        for (int q = 0; q < 16; ++q) { sv[q] = s_sbj[i * 16 + q]; m = fmaxf(m, sv[q]); }
        float sum = 0.f;
#pragma unroll
        for (int q = 0; q < 16; ++q) { sv[q] = expf(sv[q] - m); sum += sv[q]; }
        const float inv = 1.f / sum;
        float4 acc = make_float4(0.f, 0.f, 0.f, 0.f);
#pragma unroll
        for (int q = 0; q < 16; ++q) {
            const float w = sv[q] * inv;
            const float4 v = relj4[(size_t)(i * 16 + q) * 256 + t];
            acc.x += w * v.x; acc.y += w * v.y; acc.z += w * v.z; acc.w += w * v.w;
        }
        reinterpret_cast<float4*>(ctx1)[(size_t)i * 256 + t] = acc;
    } else {
        const int j = bid - 64;
        __shared__ float sl[64];
        __shared__ int el[64];
        if (t < 64) {
            const int e = conn[t * kN + j];
            el[t] = e;
            sl[t] = (e >= 0) ? s_obj[e] : -1e30f;
        }
        __syncthreads();
        float m = -1e30f;
        for (int i = 0; i < 64; ++i) m = fmaxf(m, sl[i]);
        __syncthreads();
        if (t < 64) sl[t] = (el[t] >= 0) ? expf(sl[t] - m) : 0.f;
        __syncthreads();
        float sum = 0.f;
        for (int i = 0; i < 64; ++i) sum += sl[i];
        const float inv = 1.f / sum;
        float4 acc = make_float4(0.f, 0.f, 0.f, 0.f);
        for (int i = 0; i < 64; ++i) {
            const int e = el[i];
            if (e >= 0) {
                const float w = sl[i] * inv;
                const float4 v = relj4[(size_t)e * 256 + t];
                acc.x += w * v.x; acc.y += w * v.y; acc.z += w * v.z; acc.w += w * v.w;
            }
        }
        reinterpret_cast<float4*>(ctx2)[(size_t)j * 256 + t] = acc;
    }
}

// =====================================================================
extern "C" void kernel_launch(void* const* d_in, const int* in_sizes, int n_in,
                              void* d_out, int out_size, void* d_ws, size_t ws_size,
                              hipStream_t stream)
{
    const float* visual   = (const float*)d_in[0];
    const float* relvis   = (const float*)d_in[1];
    const int*   conn     = (const int*)d_in[2];
    const int*   edge_idx = (const int*)d_in[4];
    const float* W_sub    = (const float*)d_in[5];
    const float* W_obj    = (const float*)d_in[6];
    const float* W_r2s    = (const float*)d_in[7];
    const float* W_r2o    = (const float*)d_in[8];
    const float* W_joint  = (const float*)d_in[9];
    const float* W_ctx    = (const float*)d_in[10];
    const float* W_relu   = (const float*)d_in[11];  // (D,3D): Ws|Wo|Wr
    const float* W_relj   = (const float*)d_in[12];
    const float* W_relc   = (const float*)d_in[13];
    const float* W_node   = (const float*)d_in[14];
    const float* b_node   = (const float*)d_in[15];
    const float* W_factor = (const float*)d_in[16];
    (void)in_sizes; (void)n_in; (void)out_size; (void)ws_size;

    float* ws = (float*)d_ws;
    size_t off = 0;
    auto allocF = [&](size_t n) { float* p = ws + off; off += n; return p; };
    auto allocU = [&](size_t n) { return (unsigned short*)allocF((n + 1) / 2); };

    float* part  = allocF((size_t)4 * 1024 * 1024);       // split-K partials (16 MB)
    float* asqw  = allocF((size_t)4 * 64 * 1024);         // a_s | a_o | qW_s | qW_o
    float* relj  = allocF((size_t)kE * kD);
    float* rcA   = allocF((size_t)kE * kD);
    float* rcB   = allocF((size_t)kE * kD);
    float* vctxA = allocF((size_t)kN * kD);
    float* vctxB = allocF((size_t)kN * kD);
    float* ctx1  = allocF((size_t)kN * kD);
    float* ctx2  = allocF((size_t)kN * kD);
    float* s_sbj = allocF(kE);
    float* s_obj = allocF(kE);
    unsigned short* vj_b   = allocU((size_t)kN * kD);
    unsigned short* rj_b   = allocU((size_t)kE * kD);
    unsigned short* relj_b = allocU((size_t)kE * kD);
    unsigned short* Wb_joint  = allocU((size_t)kD * 4 * kD);
    unsigned short* Wb_ctx    = allocU((size_t)kD * 3 * kD);
    unsigned short* Wb_relu   = allocU((size_t)kD * 3 * kD);
    unsigned short* Wb_relj   = allocU((size_t)kD * 4 * kD);
    unsigned short* Wb_relc   = allocU((size_t)kD * 2 * kD);
    unsigned short* Wb_node   = allocU((size_t)kD * 2 * kD);
    unsigned short* Wb_factor = allocU((size_t)kD * 2 * kD);
    unsigned short* WsubT = allocU((size_t)kD * kD);
    unsigned short* WobjT = allocU((size_t)kD * kD);
    unsigned short* Wr2sT = allocU((size_t)kD * kD);
    unsigned short* Wr2oT = allocU((size_t)kD * kD);
    unsigned short* Wc_s  = allocU((size_t)kD * kD);
    unsigned short* Wc_o  = allocU((size_t)kD * kD);

    auto reduce = [&](int MO4, int KS, float* Cf, unsigned short* Cb, const float* bias,
                      const int* eidx, const float* as_, const float* ao_) {
        hipLaunchKernelGGL(k_reduce, dim3((MO4 + 255) / 256), dim3(256), 0, stream,
                           part, MO4, KS, Cf, Cb, bias, eidx, as_, ao_);
    };
    auto bfA = [](const unsigned short* p) {
        ASrc a; a.bf = p; a.f0 = a.f1 = a.f2 = nullptr; a.mode = 0; a.dsign = 0; return a;
    };
    auto segA = [](const float* f0, const float* f1, const float* f2) {
        ASrc a; a.bf = nullptr; a.f0 = f0; a.f1 = f1; a.f2 = f2; a.mode = 1; a.dsign = 0; return a;
    };
    auto jointA = [](const float* x, const float* c, int dsign) {
        ASrc a; a.bf = nullptr; a.f0 = x; a.f1 = c; a.f2 = nullptr; a.mode = 2; a.dsign = dsign; return a;
    };
    auto g128 = [&](ASrc a, const unsigned short* W, int ldw, int K, int KS) {
        hipLaunchKernelGGL(k_gemm128, dim3(8, 8, KS), dim3(256), 0, stream, a, W, ldw, part, K, KS);
    };
    auto g64 = [&](ASrc a, SkinnyW w, int K, int KS, int nb) {
        hipLaunchKernelGGL(k_gemm64, dim3(16, 1, nb * KS), dim3(256), 0, stream, a, w, part, K, KS, nb);
    };
    auto w1 = [](const unsigned short* W, int ldw) {
        SkinnyW s; s.W[0] = W; s.ldw[0] = ldw;
        s.W[1] = s.W[2] = s.W[3] = W; s.ldw[1] = s.ldw[2] = s.ldw[3] = ldw; return s;
    };

    // ---- setup: weight conversions, transposes, combined score weights ----
    {
        ConvBatch cb;
        const float* srcs[7] = {W_joint, W_ctx, W_relu, W_relj, W_relc, W_node, W_factor};
        unsigned short* dsts[7] = {Wb_joint, Wb_ctx, Wb_relu, Wb_relj, Wb_relc, Wb_node, Wb_factor};
        const int nel[7] = {4 * 1024 * 1024, 3 * 1024 * 1024, 3 * 1024 * 1024, 4 * 1024 * 1024,
                            2 * 1024 * 1024, 2 * 1024 * 1024, 2 * 1024 * 1024};
        int cum = 0;
        for (int k = 0; k < 7; ++k) { cb.s[k] = srcs[k]; cb.d[k] = dsts[k]; cb.beg8[k] = cum; cum += nel[k] / 8; }
        cb.total8 = cum;
        hipLaunchKernelGGL(k_f2b_batch, dim3((cum + 255) / 256), dim3(256), 0, stream, cb);
    }
    {
        T4 t4;
        t4.s[0] = W_sub; t4.d[0] = WsubT;
        t4.s[1] = W_obj; t4.d[1] = WobjT;
        t4.s[2] = W_r2s; t4.d[2] = Wr2sT;
        t4.s[3] = W_r2o; t4.d[3] = Wr2oT;
        hipLaunchKernelGGL(k_transpose, dim3(16, 16, 4), dim3(256), 0, stream, t4);
    }
    // Wc_s[d,k] = sum_o W_sub[o,k] W_r2s[o,d]  (= r2sT @ subT^T)
    g128(bfA(Wr2sT), WsubT, 1024, 1024, 4);
    reduce(1024 * 1024 / 4, 4, nullptr, Wc_s, nullptr, nullptr, nullptr, nullptr);
    g128(bfA(Wr2oT), WobjT, 1024, 1024, 4);
    reduce(1024 * 1024 / 4, 4, nullptr, Wc_o, nullptr, nullptr, nullptr, nullptr);

    // ---- T iterations ----
    for (int t = 0; t < kT; ++t) {
        const float* vcur  = (t == 0) ? visual : vctxA;
        float*       vnext = (t == 0) ? vctxA : vctxB;
        const float* rccur = (t == 0) ? relvis : rcA;
        float*       rcnext = (t == 0) ? rcA : rcB;

        // vj = joint(visual, vctx) @ W_joint^T   -> bf16
        g64(jointA(visual, vcur, 1), w1(Wb_joint, 4096), 4096, 8, 1);
        reduce(64 * 1024 / 4, 8, nullptr, vj_b, nullptr, nullptr, nullptr, nullptr);

        // {a_s, a_o, qW_s, qW_o} = vj @ {Ws, Wo, Wc_s, Wc_o}^T  (one batched launch)
        {
            SkinnyW sw;
            sw.W[0] = Wb_relu;        sw.ldw[0] = 3072;
            sw.W[1] = Wb_relu + 1024; sw.ldw[1] = 3072;
            sw.W[2] = Wc_s;           sw.ldw[2] = 1024;
            sw.W[3] = Wc_o;           sw.ldw[3] = 1024;
            g64(bfA(vj_b), sw, 1024, 4, 4);
            reduce(4 * 64 * 1024 / 4, 4, asqw, nullptr, nullptr, nullptr, nullptr, nullptr);
        }

        // rj = joint(rel_temp, rel_ctx) @ W_rel_joint^T -> bf16
        g128(jointA(relvis, rccur, 0), Wb_relj, 4096, 4096, 4);
        reduce(1024 * 1024 / 4, 4, nullptr, rj_b, nullptr, nullptr, nullptr, nullptr);

        // relj = rj @ Wr^T + a_s[i] + a_o[j]   (gather-add fused in reduce)
        g128(bfA(rj_b), Wb_relu + 2048, 3072, 1024, 4);
        reduce(1024 * 1024 / 4, 4, relj, relj_b, nullptr, edge_idx, asqw, asqw + 65536);

        // scores + softmax + context aggregation
        hipLaunchKernelGGL(k_scores, dim3(kE), dim3(256), 0, stream,
                           asqw + 131072, asqw + 196608, relj, edge_idx, s_sbj, s_obj);
        hipLaunchKernelGGL(k_ctx12, dim3(128), dim3(256), 0, stream,
                           relj, s_sbj, s_obj, conn, ctx1, ctx2);

        // vctx' = [vctx, ctx1, ctx2] @ W_ctx^T
        g64(segA(vcur, ctx1, ctx2), w1(Wb_ctx, 3072), 3072, 8, 1);
        reduce(64 * 1024 / 4, 8, vnext, nullptr, nullptr, nullptr, nullptr, nullptr);

        // rel_ctx' = [rel_ctx, relj] @ W_rel_ctx^T
        g128(segA(rccur, relj, nullptr), Wb_relc, 2048, 2048, 4);
        reduce(1024 * 1024 / 4, 4, rcnext, nullptr, nullptr, nullptr, nullptr, nullptr);
    }

    float* rel_out = (float*)d_out;
    float* v_out   = (float*)d_out + (size_t)kE * kD;
    // rel_out = [rel_visual, rel_ctx] @ W_factor^T
    g128(segA(relvis, rcB, nullptr), Wb_factor, 2048, 2048, 4);
    reduce(1024 * 1024 / 4, 4, rel_out, nullptr, nullptr, nullptr, nullptr, nullptr);
    // v_out = [visual, vctx] @ W_node^T + b_node
    g64(segA(visual, vctxB, nullptr), w1(Wb_node, 2048), 2048, 8, 1);
    reduce(64 * 1024 / 4, 8, v_out, nullptr, b_node, nullptr, nullptr, nullptr);
}

// Round 5
// 368.466 us; speedup vs baseline: 1.1735x; 1.1735x over previous
//
#include <hip/hip_runtime.h>

// ---- problem constants ----
static constexpr int kN = 64;    // nodes
static constexpr int kD = 1024;  // feature dim
static constexpr int kE = 1024;  // edges (16 per row, row-major by (i,j))
static constexpr int kT = 2;     // iterations

typedef short  bf16x8 __attribute__((ext_vector_type(8)));
typedef float  f32x4  __attribute__((ext_vector_type(4)));
typedef unsigned short us8 __attribute__((ext_vector_type(8)));
typedef unsigned short us4 __attribute__((ext_vector_type(4)));

__device__ __forceinline__ unsigned short f2b(float f) {
    unsigned int u = __builtin_bit_cast(unsigned int, f);
    u += 0x7FFFu + ((u >> 16) & 1u);          // RNE
    return (unsigned short)(u >> 16);
}
__device__ __forceinline__ bf16x8 cvt8(float4 a, float4 b) {
    us8 o;
    o[0] = f2b(a.x); o[1] = f2b(a.y); o[2] = f2b(a.z); o[3] = f2b(a.w);
    o[4] = f2b(b.x); o[5] = f2b(b.y); o[6] = f2b(b.z); o[7] = f2b(b.w);
    return __builtin_bit_cast(bf16x8, o);
}
__device__ __forceinline__ float4 mul4(float4 a, float4 b) {
    return make_float4(a.x * b.x, a.y * b.y, a.z * b.z, a.w * b.w);
}

// A-operand source (bf16x8 at [row, kg:kg+8]):
// mode 0: bf16 direct, row stride 1024
// mode 1: concat of f32 segments f0|f1|f2 (each [rows][1024])
// mode 2: [f0 | f0*f1]  (two 1024 segments)
struct ASrc {
    const unsigned short* bf;
    const float* f0; const float* f1; const float* f2;
    int mode;
};

__device__ __forceinline__ bf16x8 loadA8(const ASrc& s, int row, int kg) {
    if (s.mode == 0)
        return *(const bf16x8*)(s.bf + (size_t)row * 1024 + kg);
    const int seg = kg >> 10, k = kg & 1023;
    const size_t ro = (size_t)row * 1024 + k;
    if (s.mode == 1) {
        const float* p = (seg == 0) ? s.f0 : (seg == 1 ? s.f1 : s.f2);
        return cvt8(*(const float4*)(p + ro), *(const float4*)(p + ro + 4));
    }
    // mode 2
    const float4 x0 = *(const float4*)(s.f0 + ro);
    const float4 x1 = *(const float4*)(s.f0 + ro + 4);
    if (seg == 0) return cvt8(x0, x1);
    const float4 c0 = *(const float4*)(s.f1 + ro);
    const float4 c1 = *(const float4*)(s.f1 + ro + 4);
    return cvt8(mul4(x0, c0), mul4(x1, c1));
}

// =====================================================================
// 64x64-tile MFMA GEMM, M rows x O=1024 cols: C = A @ W^T, f32 partials.
// grid (16, M/64, KS); 256 thr = 4 waves, each a 16-row stripe x 64 cols.
// LDS [64][64] bf16, 16B-chunk XOR swizzle (c8 ^ row&7), BK=64, reg prefetch.
// =====================================================================
__global__ __launch_bounds__(256)
void k_gemm_t64(ASrc As_, const unsigned short* __restrict__ W, int ldw,
                float* __restrict__ part, int M, int K, int KS)
{
    __shared__ unsigned short As[64][64];
    __shared__ unsigned short Bs[64][64];
    const int tid = threadIdx.x;
    const int lane = tid & 63, wid = tid >> 6;
    const int rowBase = blockIdx.y * 64, colBase = blockIdx.x * 64;
    const int kchunk = K / KS, kbeg = blockIdx.z * kchunk, kend = kbeg + kchunk;
    const int sr = tid >> 3, sc8 = tid & 7;
    const int wc8 = sc8 ^ (sr & 7);

    f32x4 acc[4] = {};
    const int l15 = lane & 15, l4 = lane >> 4;
    const int ar = wid * 16 + l15, asw = ar & 7;

    bf16x8 a0, a1, b0, b1;
    auto stage = [&](int kt) {
        a0 = loadA8(As_, rowBase + sr, kt + sc8 * 8);
        a1 = loadA8(As_, rowBase + sr + 32, kt + sc8 * 8);
        b0 = *(const bf16x8*)(W + (size_t)(colBase + sr) * ldw + kt + sc8 * 8);
        b1 = *(const bf16x8*)(W + (size_t)(colBase + sr + 32) * ldw + kt + sc8 * 8);
    };

    stage(kbeg);
    for (int kt = kbeg; kt < kend; kt += 64) {
        __syncthreads();
        *(bf16x8*)&As[sr][wc8 * 8] = a0;
        *(bf16x8*)&As[sr + 32][wc8 * 8] = a1;
        *(bf16x8*)&Bs[sr][wc8 * 8] = b0;
        *(bf16x8*)&Bs[sr + 32][wc8 * 8] = b1;
        __syncthreads();
        if (kt + 64 < kend) stage(kt + 64);
#pragma unroll
        for (int kk = 0; kk < 2; ++kk) {
            const int c8 = kk * 4 + l4;
            const bf16x8 af = *(const bf16x8*)&As[ar][(c8 ^ asw) * 8];
#pragma unroll
            for (int nf = 0; nf < 4; ++nf) {
                const int br = nf * 16 + l15;
                const bf16x8 bfv = *(const bf16x8*)&Bs[br][(c8 ^ (br & 7)) * 8];
                acc[nf] = __builtin_amdgcn_mfma_f32_16x16x32_bf16(af, bfv, acc[nf], 0, 0, 0);
            }
        }
    }
    float* base = part + (size_t)blockIdx.z * (size_t)M * 1024;
    const int crow = rowBase + wid * 16 + l4 * 4;
    const int ccol = colBase + l15;
#pragma unroll
    for (int nf = 0; nf < 4; ++nf)
#pragma unroll
        for (int r = 0; r < 4; ++r)
            base[(size_t)(crow + r) * 1024 + ccol + nf * 16] = acc[nf][r];
}

// =====================================================================
// skinny GEMM (M=64, O=1024), batched over nb weight sets.
// grid (16, 1, nb*KS); b = z%nb, kz = z/nb; part[(kz*nb+b)][64*1024].
// =====================================================================
struct SkinnyW { const unsigned short* W[4]; int ldw[4]; };

__global__ __launch_bounds__(256)
void k_gemm64(ASrc As_, SkinnyW Ws, float* __restrict__ part, int K, int KS, int nb)
{
    __shared__ unsigned short As[64][64];
    __shared__ unsigned short Bs[64][64];
    const int tid = threadIdx.x, lane = tid & 63, wid = tid >> 6;
    const int colBase = blockIdx.x * 64;
    const int b = blockIdx.z % nb, kz = blockIdx.z / nb;
    const unsigned short* __restrict__ W = Ws.W[b];
    const int ldw = Ws.ldw[b];
    const int kchunk = K / KS, kbeg = kz * kchunk, kend = kbeg + kchunk;
    const int sr = tid >> 3, sc8 = tid & 7;
    const int wc8 = sc8 ^ (sr & 7);

    f32x4 acc[2][2] = {};
    const int wr = wid >> 1, wc = wid & 1;
    const int l15 = lane & 15, l4 = lane >> 4;

    bf16x8 ra[2], rb[2];
    auto stage = [&](int kt) {
#pragma unroll
        for (int h = 0; h < 2; ++h) {
            ra[h] = loadA8(As_, sr + 32 * h, kt + sc8 * 8);
            rb[h] = *(const bf16x8*)(W + (size_t)(colBase + sr + 32 * h) * ldw + kt + sc8 * 8);
        }
    };

    stage(kbeg);
    for (int kt = kbeg; kt < kend; kt += 64) {
        __syncthreads();
#pragma unroll
        for (int h = 0; h < 2; ++h) {
            const int row = sr + 32 * h;
            *(bf16x8*)&As[row][wc8 * 8] = ra[h];
            *(bf16x8*)&Bs[row][wc8 * 8] = rb[h];
        }
        __syncthreads();
        if (kt + 64 < kend) stage(kt + 64);
#pragma unroll
        for (int kk = 0; kk < 2; ++kk) {
            bf16x8 af[2], bv[2];
#pragma unroll
            for (int m = 0; m < 2; ++m) {
                const int arr = wr * 32 + m * 16 + l15;
                af[m] = *(const bf16x8*)&As[arr][(((kk << 2) | l4) ^ (arr & 7)) * 8];
            }
#pragma unroll
            for (int n = 0; n < 2; ++n) {
                const int br = wc * 32 + n * 16 + l15;
                bv[n] = *(const bf16x8*)&Bs[br][(((kk << 2) | l4) ^ (br & 7)) * 8];
            }
#pragma unroll
            for (int m = 0; m < 2; ++m)
#pragma unroll
                for (int n = 0; n < 2; ++n)
                    acc[m][n] = __builtin_amdgcn_mfma_f32_16x16x32_bf16(af[m], bv[n], acc[m][n], 0, 0, 0);
        }
    }
    float* base = part + ((size_t)kz * nb + b) * (64 * 1024);
#pragma unroll
    for (int m = 0; m < 2; ++m) {
        const int row = wr * 32 + m * 16 + l4 * 4;
#pragma unroll
        for (int n = 0; n < 2; ++n) {
            const int col = colBase + wc * 32 + n * 16 + l15;
#pragma unroll
            for (int r = 0; r < 4; ++r)
                base[(size_t)(row + r) * 1024 + col] = acc[m][n][r];
        }
    }
}

// =====================================================================
// split-K reduce with fused epilogues (O = 1024 when bias/eidx used).
// out[i] = sum_z P[z][i] (+ addf[i]) (+ bias[col]) (+ a_s[i_e]+a_o[j_e])
// =====================================================================
__global__ void k_reduce(const float* __restrict__ P, int MO4, int KS,
                         float* __restrict__ Cf, unsigned short* __restrict__ Cb,
                         const float* __restrict__ addf,
                         const float* __restrict__ bias,
                         const int* __restrict__ eidx,
                         const float* __restrict__ as_, const float* __restrict__ ao_)
{
    int i = blockIdx.x * blockDim.x + threadIdx.x;
    if (i >= MO4) return;
    float4 s = make_float4(0.f, 0.f, 0.f, 0.f);
    for (int z = 0; z < KS; ++z) {
        const float4 v = reinterpret_cast<const float4*>(P)[(size_t)z * MO4 + i];
        s.x += v.x; s.y += v.y; s.z += v.z; s.w += v.w;
    }
    if (addf) {
        const float4 v = reinterpret_cast<const float4*>(addf)[i];
        s.x += v.x; s.y += v.y; s.z += v.z; s.w += v.w;
    }
    if (eidx) {
        const int e = i >> 8, c = i & 255;
        const int idx = eidx[e];
        const float4 u = reinterpret_cast<const float4*>(as_)[(size_t)(idx >> 6) * 256 + c];
        const float4 v = reinterpret_cast<const float4*>(ao_)[(size_t)(idx & 63) * 256 + c];
        s.x += u.x + v.x; s.y += u.y + v.y; s.z += u.z + v.z; s.w += u.w + v.w;
    }
    if (bias) {
        const float4 b = reinterpret_cast<const float4*>(bias)[i & 255];
        s.x += b.x; s.y += b.y; s.z += b.z; s.w += b.w;
    }
    if (Cf) reinterpret_cast<float4*>(Cf)[i] = s;
    if (Cb) {
        us4 o; o.x = f2b(s.x); o.y = f2b(s.y); o.z = f2b(s.z); o.w = f2b(s.w);
        *(us4*)(Cb + (size_t)i * 4) = o;
    }
}

// batched f32 -> bf16 conversion (5 weight matrices), one launch
struct ConvBatch {
    const float* s[5];
    unsigned short* d[5];
    int beg8[5];
    int total8;
};
__global__ void k_f2b_batch(ConvBatch cb)
{
    int i = blockIdx.x * blockDim.x + threadIdx.x;
    if (i >= cb.total8) return;
    int k = 0;
    while (k < 4 && i >= cb.beg8[k + 1]) ++k;
    const int j = i - cb.beg8[k];
    const float4 v0 = reinterpret_cast<const float4*>(cb.s[k])[2 * j];
    const float4 v1 = reinterpret_cast<const float4*>(cb.s[k])[2 * j + 1];
    const bf16x8 o = cvt8(v0, v1);
    *(bf16x8*)(cb.d[k] + (size_t)j * 8) = o;
}

// transpose 4 f32 [1024][1024] matrices into bf16 (dst[k][o] = src[o][k])
struct T4 { const float* s[4]; unsigned short* d[4]; };
__global__ __launch_bounds__(256)
void k_transpose(T4 t4)
{
    __shared__ float tile[64][65];
    const float* __restrict__ src = t4.s[blockIdx.z];
    unsigned short* __restrict__ dst = t4.d[blockIdx.z];
    const int bx = blockIdx.x * 64, by = blockIdx.y * 64;
    const int c = threadIdx.x & 63, r0 = threadIdx.x >> 6;
#pragma unroll
    for (int h = 0; h < 16; ++h) {
        const int r = r0 * 16 + h;
        tile[r][c] = src[(size_t)(by + r) * 1024 + bx + c];
    }
    __syncthreads();
#pragma unroll
    for (int h = 0; h < 16; ++h) {
        const int kk = r0 * 16 + h;
        dst[(size_t)(bx + kk) * 1024 + by + c] = f2b(tile[c][kk]);
    }
}

// build folded joint weights from W (1024 x 4096, slices W1|W2|W3|W4):
// z=0 (rel, s=+1):  rt = W1+W4,  eff = [W2-W4 | W3]
// z=1 (vj,  s=-1):  rt = W1-W4,  eff = [W2+W4 | W3]
__global__ __launch_bounds__(256)
void k_buildW(const float* __restrict__ Wrel, const float* __restrict__ Wjnt,
              unsigned short* __restrict__ WrtRel, unsigned short* __restrict__ WeffRel,
              unsigned short* __restrict__ UrtVj, unsigned short* __restrict__ UeffVj)
{
    const int idx = blockIdx.x * 256 + threadIdx.x;     // [0, 1024*256)
    const int o = idx >> 8, j = (idx & 255) * 4;
    const float* W = blockIdx.z ? Wjnt : Wrel;
    const float sgn = blockIdx.z ? -1.f : 1.f;
    unsigned short* rt = blockIdx.z ? UrtVj : WrtRel;
    unsigned short* ef = blockIdx.z ? UeffVj : WeffRel;
    const float4 w1 = *(const float4*)(W + (size_t)o * 4096 + j);
    const float4 w2 = *(const float4*)(W + (size_t)o * 4096 + 1024 + j);
    const float4 w3 = *(const float4*)(W + (size_t)o * 4096 + 2048 + j);
    const float4 w4 = *(const float4*)(W + (size_t)o * 4096 + 3072 + j);
    us4 t;
    t.x = f2b(w1.x + sgn * w4.x); t.y = f2b(w1.y + sgn * w4.y);
    t.z = f2b(w1.z + sgn * w4.z); t.w = f2b(w1.w + sgn * w4.w);
    *(us4*)(rt + (size_t)o * 1024 + j) = t;
    t.x = f2b(w2.x - sgn * w4.x); t.y = f2b(w2.y - sgn * w4.y);
    t.z = f2b(w2.z - sgn * w4.z); t.w = f2b(w2.w - sgn * w4.w);
    *(us4*)(ef + (size_t)o * 2048 + j) = t;
    t.x = f2b(w3.x); t.y = f2b(w3.y); t.z = f2b(w3.z); t.w = f2b(w3.w);
    *(us4*)(ef + (size_t)o * 2048 + 1024 + j) = t;
}

// s_sbj[e] = <qW_s[i_e], relj[e]>/32 ; s_obj[e] = <qW_o[j_e], relj[e]>/32
__global__ __launch_bounds__(256)
void k_scores(const float* __restrict__ qws, const float* __restrict__ qwo,
              const float* __restrict__ relj, const int* __restrict__ eidx,
              float* __restrict__ s_sbj, float* __restrict__ s_obj)
{
    const int e = blockIdx.x, t = threadIdx.x;
    const int idx = eidx[e];
    const int i = idx >> 6, j = idx & 63;
    const float4 r = reinterpret_cast<const float4*>(relj)[(size_t)e * 256 + t];
    const float4 a = reinterpret_cast<const float4*>(qws)[(size_t)i * 256 + t];
    const float4 b = reinterpret_cast<const float4*>(qwo)[(size_t)j * 256 + t];
    float vs = a.x * r.x + a.y * r.y + a.z * r.z + a.w * r.w;
    float vo = b.x * r.x + b.y * r.y + b.z * r.z + b.w * r.w;
    for (int off = 32; off; off >>= 1) {
        vs += __shfl_down(vs, off);
        vo += __shfl_down(vo, off);
    }
    __shared__ float ss[4], so[4];
    const int w = t >> 6, lane = t & 63;
    if (lane == 0) { ss[w] = vs; so[w] = vo; }
    __syncthreads();
    if (t == 0) {
        s_sbj[e] = (ss[0] + ss[1] + ss[2] + ss[3]) * 0.03125f;
        s_obj[e] = (so[0] + so[1] + so[2] + so[3]) * 0.03125f;
    }
}

// fused softmax + weighted aggregation (ctx1 rows / ctx2 cols)
__global__ __launch_bounds__(256)
void k_ctx12(const float* __restrict__ relj, const float* __restrict__ s_sbj,
             const float* __restrict__ s_obj, const int* __restrict__ conn,
             float* __restrict__ ctx1, float* __restrict__ ctx2)
{
    const int bid = blockIdx.x, t = threadIdx.x;
    const float4* relj4 = reinterpret_cast<const float4*>(relj);
    if (bid < 64) {
        const int i = bid;
        float sv[16];
        float m = -1e30f;
#pragma unroll
        for (int q = 0; q < 16; ++q) { sv[q] = s_sbj[i * 16 + q]; m = fmaxf(m, sv[q]); }
        float sum = 0.f;
#pragma unroll
        for (int q = 0; q < 16; ++q) { sv[q] = expf(sv[q] - m); sum += sv[q]; }
        const float inv = 1.f / sum;
        float4 acc = make_float4(0.f, 0.f, 0.f, 0.f);
#pragma unroll
        for (int q = 0; q < 16; ++q) {
            const float w = sv[q] * inv;
            const float4 v = relj4[(size_t)(i * 16 + q) * 256 + t];
            acc.x += w * v.x; acc.y += w * v.y; acc.z += w * v.z; acc.w += w * v.w;
        }
        reinterpret_cast<float4*>(ctx1)[(size_t)i * 256 + t] = acc;
    } else {
        const int j = bid - 64;
        __shared__ float sl[64];
        __shared__ int el[64];
        if (t < 64) {
            const int e = conn[t * kN + j];
            el[t] = e;
            sl[t] = (e >= 0) ? s_obj[e] : -1e30f;
        }
        __syncthreads();
        float m = -1e30f;
        for (int i = 0; i < 64; ++i) m = fmaxf(m, sl[i]);
        __syncthreads();
        if (t < 64) sl[t] = (el[t] >= 0) ? expf(sl[t] - m) : 0.f;
        __syncthreads();
        float sum = 0.f;
        for (int i = 0; i < 64; ++i) sum += sl[i];
        const float inv = 1.f / sum;
        float4 acc = make_float4(0.f, 0.f, 0.f, 0.f);
        for (int i = 0; i < 64; ++i) {
            const int e = el[i];
            if (e >= 0) {
                const float w = sl[i] * inv;
                const float4 v = relj4[(size_t)e * 256 + t];
                acc.x += w * v.x; acc.y += w * v.y; acc.z += w * v.z; acc.w += w * v.w;
            }
        }
        reinterpret_cast<float4*>(ctx2)[(size_t)j * 256 + t] = acc;
    }
}

// =====================================================================
extern "C" void kernel_launch(void* const* d_in, const int* in_sizes, int n_in,
                              void* d_out, int out_size, void* d_ws, size_t ws_size,
                              hipStream_t stream)
{
    const float* visual   = (const float*)d_in[0];
    const float* relvis   = (const float*)d_in[1];
    const int*   conn     = (const int*)d_in[2];
    const int*   edge_idx = (const int*)d_in[4];
    const float* W_sub    = (const float*)d_in[5];
    const float* W_obj    = (const float*)d_in[6];
    const float* W_r2s    = (const float*)d_in[7];
    const float* W_r2o    = (const float*)d_in[8];
    const float* W_joint  = (const float*)d_in[9];
    const float* W_ctx    = (const float*)d_in[10];
    const float* W_relu   = (const float*)d_in[11];  // (D,3D): Ws|Wo|Wr
    const float* W_relj   = (const float*)d_in[12];
    const float* W_relc   = (const float*)d_in[13];
    const float* W_node   = (const float*)d_in[14];
    const float* b_node   = (const float*)d_in[15];
    const float* W_factor = (const float*)d_in[16];
    (void)in_sizes; (void)n_in; (void)out_size; (void)ws_size;

    float* ws = (float*)d_ws;
    size_t off = 0;
    auto allocF = [&](size_t n) { float* p = ws + off; off += n; return p; };
    auto allocU = [&](size_t n) { return (unsigned short*)allocF((n + 1) / 2); };

    float* part  = allocF((size_t)4 * 1024 * 1024);   // split-K partials (16 MB)
    float* asqw  = allocF((size_t)4 * 64 * 1024);     // a_s | a_o | qW_s | qW_o
    float* relj  = allocF((size_t)kE * kD);
    float* rj    = allocF((size_t)kE * kD);
    float* R0    = allocF((size_t)kE * kD);           // relvis @ (W1+W4)^T
    float* rcA   = allocF((size_t)kE * kD);
    float* rcB   = allocF((size_t)kE * kD);
    float* G0    = allocF((size_t)kN * kD);           // visual @ (U1-U4)^T
    float* vj    = allocF((size_t)kN * kD);
    float* vctxA = allocF((size_t)kN * kD);
    float* vctxB = allocF((size_t)kN * kD);
    float* ctx1  = allocF((size_t)kN * kD);
    float* ctx2  = allocF((size_t)kN * kD);
    float* s_sbj = allocF(kE);
    float* s_obj = allocF(kE);
    unsigned short* Wb_ctx    = allocU((size_t)kD * 3 * kD);
    unsigned short* Wb_relu   = allocU((size_t)kD * 3 * kD);
    unsigned short* Wb_relc   = allocU((size_t)kD * 2 * kD);
    unsigned short* Wb_node   = allocU((size_t)kD * 2 * kD);
    unsigned short* Wb_factor = allocU((size_t)kD * 2 * kD);
    unsigned short* WsubT = allocU((size_t)kD * kD);
    unsigned short* WobjT = allocU((size_t)kD * kD);
    unsigned short* Wr2sT = allocU((size_t)kD * kD);
    unsigned short* Wr2oT = allocU((size_t)kD * kD);
    unsigned short* Wc_s  = allocU((size_t)kD * kD);
    unsigned short* Wc_o  = allocU((size_t)kD * kD);
    unsigned short* WrtRel  = allocU((size_t)kD * kD);      // W1+W4
    unsigned short* WeffRel = allocU((size_t)kD * 2 * kD);  // [W2-W4 | W3]
    unsigned short* UrtVj   = allocU((size_t)kD * kD);      // U1-U4
    unsigned short* UeffVj  = allocU((size_t)kD * 2 * kD);  // [U2+U4 | U3]

    auto bfA = [](const unsigned short* p) {
        ASrc a; a.bf = p; a.f0 = a.f1 = a.f2 = nullptr; a.mode = 0; return a;
    };
    auto segA = [](const float* f0, const float* f1, const float* f2) {
        ASrc a; a.bf = nullptr; a.f0 = f0; a.f1 = f1; a.f2 = f2; a.mode = 1; return a;
    };
    auto prodA = [](const float* c, const float* x) {  // [c | c*x]
        ASrc a; a.bf = nullptr; a.f0 = c; a.f1 = x; a.f2 = nullptr; a.mode = 2; return a;
    };
    auto g1024 = [&](ASrc a, const unsigned short* W, int ldw, int K, int KS) {
        hipLaunchKernelGGL(k_gemm_t64, dim3(16, 16, KS), dim3(256), 0, stream,
                           a, W, ldw, part, 1024, K, KS);
    };
    auto g64 = [&](ASrc a, SkinnyW w, int K, int KS, int nb) {
        hipLaunchKernelGGL(k_gemm64, dim3(16, 1, nb * KS), dim3(256), 0, stream,
                           a, w, part, K, KS, nb);
    };
    auto w1 = [](const unsigned short* W, int ldw) {
        SkinnyW s; s.W[0] = W; s.ldw[0] = ldw;
        s.W[1] = s.W[2] = s.W[3] = W; s.ldw[1] = s.ldw[2] = s.ldw[3] = ldw; return s;
    };
    auto reduce = [&](int MO4, int KS, float* Cf, unsigned short* Cb, const float* addf,
                      const float* bias, const int* eidx, const float* as_, const float* ao_) {
        hipLaunchKernelGGL(k_reduce, dim3((MO4 + 255) / 256), dim3(256), 0, stream,
                           part, MO4, KS, Cf, Cb, addf, bias, eidx, as_, ao_);
    };

    // ---- setup ----
    {
        ConvBatch cb;
        const float* srcs[5] = {W_ctx, W_relu, W_relc, W_node, W_factor};
        unsigned short* dsts[5] = {Wb_ctx, Wb_relu, Wb_relc, Wb_node, Wb_factor};
        const int nel[5] = {3 * 1024 * 1024, 3 * 1024 * 1024, 2 * 1024 * 1024,
                            2 * 1024 * 1024, 2 * 1024 * 1024};
        int cum = 0;
        for (int k = 0; k < 5; ++k) { cb.s[k] = srcs[k]; cb.d[k] = dsts[k]; cb.beg8[k] = cum; cum += nel[k] / 8; }
        cb.total8 = cum;
        hipLaunchKernelGGL(k_f2b_batch, dim3((cum + 255) / 256), dim3(256), 0, stream, cb);
    }
    {
        T4 t4;
        t4.s[0] = W_sub; t4.d[0] = WsubT;
        t4.s[1] = W_obj; t4.d[1] = WobjT;
        t4.s[2] = W_r2s; t4.d[2] = Wr2sT;
        t4.s[3] = W_r2o; t4.d[3] = Wr2oT;
        hipLaunchKernelGGL(k_transpose, dim3(16, 16, 4), dim3(256), 0, stream, t4);
    }
    hipLaunchKernelGGL(k_buildW, dim3(1024, 1, 2), dim3(256), 0, stream,
                       W_relj, W_joint, WrtRel, WeffRel, UrtVj, UeffVj);
    // Wc_s[d,k] = sum_o W_sub[o,k] W_r2s[o,d]  (= r2sT @ subT^T); same for obj
    g1024(bfA(Wr2sT), WsubT, 1024, 1024, 4);
    reduce(262144, 4, nullptr, Wc_s, nullptr, nullptr, nullptr, nullptr, nullptr);
    g1024(bfA(Wr2oT), WobjT, 1024, 1024, 4);
    reduce(262144, 4, nullptr, Wc_o, nullptr, nullptr, nullptr, nullptr, nullptr);
    // R0 = relvis @ (W1+W4)^T ; G0 = visual @ (U1-U4)^T
    g1024(segA(relvis, nullptr, nullptr), WrtRel, 1024, 1024, 4);
    reduce(262144, 4, R0, nullptr, nullptr, nullptr, nullptr, nullptr, nullptr);
    g64(segA(visual, nullptr, nullptr), w1(UrtVj, 1024), 1024, 8, 1);
    reduce(16384, 8, G0, nullptr, nullptr, nullptr, nullptr, nullptr, nullptr);

    // ---- T iterations ----
    for (int t = 0; t < kT; ++t) {
        const float* vcur   = (t == 0) ? visual : vctxA;
        float*       vnext  = (t == 0) ? vctxA : vctxB;
        const float* rccur  = (t == 0) ? relvis : rcA;
        float*       rcnext = (t == 0) ? rcA : rcB;

        // vj = G0 + [vctx, visual*vctx] @ [U2+U4 | U3]^T
        g64(prodA(vcur, visual), w1(UeffVj, 2048), 2048, 8, 1);
        reduce(16384, 8, vj, nullptr, G0, nullptr, nullptr, nullptr, nullptr);

        // {a_s, a_o, qW_s, qW_o} = vj @ {Ws, Wo, Wc_s, Wc_o}^T  (one batched launch)
        {
            SkinnyW sw;
            sw.W[0] = Wb_relu;        sw.ldw[0] = 3072;
            sw.W[1] = Wb_relu + 1024; sw.ldw[1] = 3072;
            sw.W[2] = Wc_s;           sw.ldw[2] = 1024;
            sw.W[3] = Wc_o;           sw.ldw[3] = 1024;
            g64(segA(vj, nullptr, nullptr), sw, 1024, 2, 4);
            reduce(65536, 2, asqw, nullptr, nullptr, nullptr, nullptr, nullptr, nullptr);
        }

        // rj = R0 + [rc, relvis*rc] @ [W2-W4 | W3]^T
        g1024(prodA(rccur, relvis), WeffRel, 2048, 2048, 4);
        reduce(262144, 4, rj, nullptr, R0, nullptr, nullptr, nullptr, nullptr);

        // relj = rj @ Wr^T + a_s[i] + a_o[j]
        g1024(segA(rj, nullptr, nullptr), Wb_relu + 2048, 3072, 1024, 4);
        reduce(262144, 4, relj, nullptr, nullptr, nullptr, edge_idx, asqw, asqw + 65536);

        // scores + softmax + context aggregation
        hipLaunchKernelGGL(k_scores, dim3(kE), dim3(256), 0, stream,
                           asqw + 131072, asqw + 196608, relj, edge_idx, s_sbj, s_obj);
        hipLaunchKernelGGL(k_ctx12, dim3(128), dim3(256), 0, stream,
                           relj, s_sbj, s_obj, conn, ctx1, ctx2);

        // vctx' = [vctx, ctx1, ctx2] @ W_ctx^T
        g64(segA(vcur, ctx1, ctx2), w1(Wb_ctx, 3072), 3072, 8, 1);
        reduce(16384, 8, vnext, nullptr, nullptr, nullptr, nullptr, nullptr, nullptr);

        // rel_ctx' = [rel_ctx, relj] @ W_rel_ctx^T
        g1024(segA(rccur, relj, nullptr), Wb_relc, 2048, 2048, 4);
        reduce(262144, 4, rcnext, nullptr, nullptr, nullptr, nullptr, nullptr, nullptr);
    }

    float* rel_out = (float*)d_out;
    float* v_out   = (float*)d_out + (size_t)kE * kD;
    // rel_out = [rel_visual, rel_ctx] @ W_factor^T
    g1024(segA(relvis, rcB, nullptr), Wb_factor, 2048, 2048, 4);
    reduce(262144, 4, rel_out, nullptr, nullptr, nullptr, nullptr, nullptr, nullptr);
    // v_out = [visual, vctx] @ W_node^T + b_node
    g64(segA(visual, vctxB, nullptr), w1(Wb_node, 2048), 2048, 8, 1);
    reduce(16384, 8, v_out, nullptr, nullptr, b_node, nullptr, nullptr, nullptr);
}

// Round 6
// 361.419 us; speedup vs baseline: 1.1963x; 1.0195x over previous
//
#include <hip/hip_runtime.h>

// ---- problem constants ----
static constexpr int kN = 64;    // nodes
static constexpr int kD = 1024;  // feature dim
static constexpr int kE = 1024;  // edges (16 per row, row-major by (i,j))
static constexpr int kT = 2;     // iterations

typedef short  bf16x8 __attribute__((ext_vector_type(8)));
typedef float  f32x4  __attribute__((ext_vector_type(4)));
typedef unsigned short us8 __attribute__((ext_vector_type(8)));
typedef unsigned short us4 __attribute__((ext_vector_type(4)));

__device__ __forceinline__ unsigned short f2b(float f) {
    unsigned int u = __builtin_bit_cast(unsigned int, f);
    u += 0x7FFFu + ((u >> 16) & 1u);          // RNE
    return (unsigned short)(u >> 16);
}
__device__ __forceinline__ bf16x8 cvt8(float4 a, float4 b) {
    us8 o;
    o[0] = f2b(a.x); o[1] = f2b(a.y); o[2] = f2b(a.z); o[3] = f2b(a.w);
    o[4] = f2b(b.x); o[5] = f2b(b.y); o[6] = f2b(b.z); o[7] = f2b(b.w);
    return __builtin_bit_cast(bf16x8, o);
}
__device__ __forceinline__ float4 mul4(float4 a, float4 b) {
    return make_float4(a.x * b.x, a.y * b.y, a.z * b.z, a.w * b.w);
}

// A-operand source (bf16x8 at [row, kg:kg+8]):
// mode 0: bf16 direct, row stride 1024
// mode 1: concat of f32 segments f0|f1|f2 (each [rows][1024])
// mode 2: [f0 | f0*f1]  (two 1024 segments)
struct ASrc {
    const unsigned short* bf;
    const float* f0; const float* f1; const float* f2;
    int mode;
};

__device__ __forceinline__ bf16x8 loadA8(const ASrc& s, int row, int kg) {
    if (s.mode == 0)
        return *(const bf16x8*)(s.bf + (size_t)row * 1024 + kg);
    const int seg = kg >> 10, k = kg & 1023;
    const size_t ro = (size_t)row * 1024 + k;
    if (s.mode == 1) {
        const float* p = (seg == 0) ? s.f0 : (seg == 1 ? s.f1 : s.f2);
        return cvt8(*(const float4*)(p + ro), *(const float4*)(p + ro + 4));
    }
    const float4 x0 = *(const float4*)(s.f0 + ro);
    const float4 x1 = *(const float4*)(s.f0 + ro + 4);
    if (seg == 0) return cvt8(x0, x1);
    const float4 c0 = *(const float4*)(s.f1 + ro);
    const float4 c1 = *(const float4*)(s.f1 + ro + 4);
    return cvt8(mul4(x0, c0), mul4(x1, c1));
}

// =====================================================================
// Job-list MFMA GEMM. Each job: C_partial[z] = A[M,K-chunk] @ W[O=1024,K]^T.
// Block tile 64 rows x 128 cols; 4 waves (2x2), each 32x64 (8 MFMA / 6 reads
// per half-K-step). LDS XOR-swizzled. Tiles per job = KS * (M/64) * 8.
// =====================================================================
struct GJob { ASrc a; const unsigned short* W; int ldw; float* P; int M; int K; int KS; };
struct GJobs { GJob j[5]; int t0[6]; int nj; };

__global__ __launch_bounds__(256)
void k_gemm(GJobs G)
{
    __shared__ unsigned short As[64][64];
    __shared__ unsigned short Bs[128][64];
    const int flat = blockIdx.x;
    int ji = 0;
    while (ji + 1 < G.nj && flat >= G.t0[ji + 1]) ++ji;
    const GJob J = G.j[ji];
    const int local = flat - G.t0[ji];
    const int rowTiles = J.M >> 6;
    const int perKS = rowTiles * 8;
    const int z = local / perKS, rc_ = local % perKS;
    const int rowBase = (rc_ >> 3) * 64, colBase = (rc_ & 7) * 128;
    const int kchunk = J.K / J.KS, kbeg = z * kchunk, kend = kbeg + kchunk;

    const int tid = threadIdx.x, lane = tid & 63, wid = tid >> 6;
    const int sr = tid >> 3, sc8 = tid & 7;
    const int wc8 = (sc8 ^ (sr & 7)) * 8;

    bf16x8 ra[2], rb[4];
    auto stage = [&](int kt) {
#pragma unroll
        for (int h = 0; h < 2; ++h)
            ra[h] = loadA8(J.a, rowBase + sr + 32 * h, kt + sc8 * 8);
#pragma unroll
        for (int h = 0; h < 4; ++h)
            rb[h] = *(const bf16x8*)(J.W + (size_t)(colBase + sr + 32 * h) * J.ldw + kt + sc8 * 8);
    };

    f32x4 acc[2][4] = {};
    const int wr = wid >> 1, wc = wid & 1;
    const int l15 = lane & 15, l4 = lane >> 4;

    stage(kbeg);
    for (int kt = kbeg; kt < kend; kt += 64) {
        __syncthreads();
#pragma unroll
        for (int h = 0; h < 2; ++h)
            *(bf16x8*)&As[sr + 32 * h][wc8] = ra[h];
#pragma unroll
        for (int h = 0; h < 4; ++h)
            *(bf16x8*)&Bs[sr + 32 * h][wc8] = rb[h];
        __syncthreads();
        if (kt + 64 < kend) stage(kt + 64);
#pragma unroll
        for (int kk = 0; kk < 2; ++kk) {
            const int c8 = kk * 4 + l4;
            bf16x8 af[2], bv[4];
#pragma unroll
            for (int m = 0; m < 2; ++m) {
                const int ar = wr * 32 + m * 16 + l15;
                af[m] = *(const bf16x8*)&As[ar][(c8 ^ (ar & 7)) * 8];
            }
#pragma unroll
            for (int n = 0; n < 4; ++n) {
                const int br = wc * 64 + n * 16 + l15;
                bv[n] = *(const bf16x8*)&Bs[br][(c8 ^ (br & 7)) * 8];
            }
#pragma unroll
            for (int m = 0; m < 2; ++m)
#pragma unroll
                for (int n = 0; n < 4; ++n)
                    acc[m][n] = __builtin_amdgcn_mfma_f32_16x16x32_bf16(af[m], bv[n], acc[m][n], 0, 0, 0);
        }
    }
    float* base = J.P + (size_t)z * (size_t)J.M * 1024;
#pragma unroll
    for (int m = 0; m < 2; ++m) {
        const int row = rowBase + wr * 32 + m * 16 + l4 * 4;
#pragma unroll
        for (int n = 0; n < 4; ++n) {
            const int col = colBase + wc * 64 + n * 16 + l15;
#pragma unroll
            for (int r = 0; r < 4; ++r)
                base[(size_t)(row + r) * 1024 + col] = acc[m][n][r];
        }
    }
}

// =====================================================================
// Job-list split-K reduce with fused epilogues.
// out[i] = sum_z P[z][i] (+ addf) (+ bias) (+ gather a_s[i_e]+a_o[j_e]
//   summed from asqw PARTIALS at gP: a_s = gP + z*64K, a_o = gP + 128K + z*64K)
// =====================================================================
struct RJob { const float* P; int MO4; int KS; float* Cf; unsigned short* Cb;
              const float* addf; const float* bias; int gather; };
struct RJobs { RJob j[5]; int t0[6]; int nj; const int* eidx; const float* gP; int gKS; };

__global__ void k_reduce(RJobs R)
{
    const int flat = blockIdx.x;
    int ji = 0;
    while (ji + 1 < R.nj && flat >= R.t0[ji + 1]) ++ji;
    const RJob J = R.j[ji];
    const int i = (flat - R.t0[ji]) * 256 + threadIdx.x;
    if (i >= J.MO4) return;
    float4 s = make_float4(0.f, 0.f, 0.f, 0.f);
    for (int z = 0; z < J.KS; ++z) {
        const float4 v = reinterpret_cast<const float4*>(J.P)[(size_t)z * J.MO4 + i];
        s.x += v.x; s.y += v.y; s.z += v.z; s.w += v.w;
    }
    if (J.addf) {
        const float4 v = reinterpret_cast<const float4*>(J.addf)[i];
        s.x += v.x; s.y += v.y; s.z += v.z; s.w += v.w;
    }
    if (J.gather) {
        const int e = i >> 8, c = i & 255;
        const int idx = R.eidx[e];
        const int ri = (idx >> 6) * 256 + c;
        const int rjx = (idx & 63) * 256 + c;
        const float4* g4 = reinterpret_cast<const float4*>(R.gP);
        for (int z = 0; z < R.gKS; ++z) {
            const float4 u = g4[(size_t)z * 16384 + ri];
            const float4 v = g4[32768 + (size_t)z * 16384 + rjx];
            s.x += u.x + v.x; s.y += u.y + v.y; s.z += u.z + v.z; s.w += u.w + v.w;
        }
    }
    if (J.bias) {
        const float4 b = reinterpret_cast<const float4*>(J.bias)[i & 255];
        s.x += b.x; s.y += b.y; s.z += b.z; s.w += b.w;
    }
    if (J.Cf) reinterpret_cast<float4*>(J.Cf)[i] = s;
    if (J.Cb) {
        us4 o; o.x = f2b(s.x); o.y = f2b(s.y); o.z = f2b(s.z); o.w = f2b(s.w);
        *(us4*)(J.Cb + (size_t)i * 4) = o;
    }
}

// batched f32 -> bf16 conversion (5 weight matrices), one launch
struct ConvBatch {
    const float* s[5];
    unsigned short* d[5];
    int beg8[5];
    int total8;
};
__global__ void k_f2b_batch(ConvBatch cb)
{
    int i = blockIdx.x * blockDim.x + threadIdx.x;
    if (i >= cb.total8) return;
    int k = 0;
    while (k < 4 && i >= cb.beg8[k + 1]) ++k;
    const int j = i - cb.beg8[k];
    const float4 v0 = reinterpret_cast<const float4*>(cb.s[k])[2 * j];
    const float4 v1 = reinterpret_cast<const float4*>(cb.s[k])[2 * j + 1];
    const bf16x8 o = cvt8(v0, v1);
    *(bf16x8*)(cb.d[k] + (size_t)j * 8) = o;
}

// transpose 4 f32 [1024][1024] matrices into bf16 (dst[k][o] = src[o][k])
struct T4 { const float* s[4]; unsigned short* d[4]; };
__global__ __launch_bounds__(256)
void k_transpose(T4 t4)
{
    __shared__ float tile[64][65];
    const float* __restrict__ src = t4.s[blockIdx.z];
    unsigned short* __restrict__ dst = t4.d[blockIdx.z];
    const int bx = blockIdx.x * 64, by = blockIdx.y * 64;
    const int c = threadIdx.x & 63, r0 = threadIdx.x >> 6;
#pragma unroll
    for (int h = 0; h < 16; ++h) {
        const int r = r0 * 16 + h;
        tile[r][c] = src[(size_t)(by + r) * 1024 + bx + c];
    }
    __syncthreads();
#pragma unroll
    for (int h = 0; h < 16; ++h) {
        const int kk = r0 * 16 + h;
        dst[(size_t)(bx + kk) * 1024 + by + c] = f2b(tile[c][kk]);
    }
}

// build folded joint weights from W (1024 x 4096, slices W1|W2|W3|W4):
// z=0 (rel, s=+1):  rt = W1+W4,  eff = [W2-W4 | W3]
// z=1 (vj,  s=-1):  rt = W1-W4,  eff = [W2+W4 | W3]
__global__ __launch_bounds__(256)
void k_buildW(const float* __restrict__ Wrel, const float* __restrict__ Wjnt,
              unsigned short* __restrict__ WrtRel, unsigned short* __restrict__ WeffRel,
              unsigned short* __restrict__ UrtVj, unsigned short* __restrict__ UeffVj)
{
    const int idx = blockIdx.x * 256 + threadIdx.x;     // [0, 1024*256)
    const int o = idx >> 8, j = (idx & 255) * 4;
    const float* W = blockIdx.z ? Wjnt : Wrel;
    const float sgn = blockIdx.z ? -1.f : 1.f;
    unsigned short* rt = blockIdx.z ? UrtVj : WrtRel;
    unsigned short* ef = blockIdx.z ? UeffVj : WeffRel;
    const float4 w1 = *(const float4*)(W + (size_t)o * 4096 + j);
    const float4 w2 = *(const float4*)(W + (size_t)o * 4096 + 1024 + j);
    const float4 w3 = *(const float4*)(W + (size_t)o * 4096 + 2048 + j);
    const float4 w4 = *(const float4*)(W + (size_t)o * 4096 + 3072 + j);
    us4 t;
    t.x = f2b(w1.x + sgn * w4.x); t.y = f2b(w1.y + sgn * w4.y);
    t.z = f2b(w1.z + sgn * w4.z); t.w = f2b(w1.w + sgn * w4.w);
    *(us4*)(rt + (size_t)o * 1024 + j) = t;
    t.x = f2b(w2.x - sgn * w4.x); t.y = f2b(w2.y - sgn * w4.y);
    t.z = f2b(w2.z - sgn * w4.z); t.w = f2b(w2.w - sgn * w4.w);
    *(us4*)(ef + (size_t)o * 2048 + j) = t;
    t.x = f2b(w3.x); t.y = f2b(w3.y); t.z = f2b(w3.z); t.w = f2b(w3.w);
    *(us4*)(ef + (size_t)o * 2048 + 1024 + j) = t;
}

// s_sbj[e] = <qW_s[i_e], relj[e]>/32 ; s_obj[e] = <qW_o[j_e], relj[e]>/32
__global__ __launch_bounds__(256)
void k_scores(const float* __restrict__ qws, const float* __restrict__ qwo,
              const float* __restrict__ relj, const int* __restrict__ eidx,
              float* __restrict__ s_sbj, float* __restrict__ s_obj)
{
    const int e = blockIdx.x, t = threadIdx.x;
    const int idx = eidx[e];
    const int i = idx >> 6, j = idx & 63;
    const float4 r = reinterpret_cast<const float4*>(relj)[(size_t)e * 256 + t];
    const float4 a = reinterpret_cast<const float4*>(qws)[(size_t)i * 256 + t];
    const float4 b = reinterpret_cast<const float4*>(qwo)[(size_t)j * 256 + t];
    float vs = a.x * r.x + a.y * r.y + a.z * r.z + a.w * r.w;
    float vo = b.x * r.x + b.y * r.y + b.z * r.z + b.w * r.w;
    for (int off = 32; off; off >>= 1) {
        vs += __shfl_down(vs, off);
        vo += __shfl_down(vo, off);
    }
    __shared__ float ss[4], so[4];
    const int w = t >> 6, lane = t & 63;
    if (lane == 0) { ss[w] = vs; so[w] = vo; }
    __syncthreads();
    if (t == 0) {
        s_sbj[e] = (ss[0] + ss[1] + ss[2] + ss[3]) * 0.03125f;
        s_obj[e] = (so[0] + so[1] + so[2] + so[3]) * 0.03125f;
    }
}

// fused softmax + weighted aggregation (ctx1 rows / ctx2 cols)
__global__ __launch_bounds__(256)
void k_ctx12(const float* __restrict__ relj, const float* __restrict__ s_sbj,
             const float* __restrict__ s_obj, const int* __restrict__ conn,
             float* __restrict__ ctx1, float* __restrict__ ctx2)
{
    const int bid = blockIdx.x, t = threadIdx.x;
    const float4* relj4 = reinterpret_cast<const float4*>(relj);
    if (bid < 64) {
        const int i = bid;
        float sv[16];
        float m = -1e30f;
#pragma unroll
        for (int q = 0; q < 16; ++q) { sv[q] = s_sbj[i * 16 + q]; m = fmaxf(m, sv[q]); }
        float sum = 0.f;
#pragma unroll
        for (int q = 0; q < 16; ++q) { sv[q] = expf(sv[q] - m); sum += sv[q]; }
        const float inv = 1.f / sum;
        float4 acc = make_float4(0.f, 0.f, 0.f, 0.f);
#pragma unroll
        for (int q = 0; q < 16; ++q) {
            const float w = sv[q] * inv;
            const float4 v = relj4[(size_t)(i * 16 + q) * 256 + t];
            acc.x += w * v.x; acc.y += w * v.y; acc.z += w * v.z; acc.w += w * v.w;
        }
        reinterpret_cast<float4*>(ctx1)[(size_t)i * 256 + t] = acc;
    } else {
        const int j = bid - 64;
        __shared__ float sl[64];
        __shared__ int el[64];
        if (t < 64) {
            const int e = conn[t * kN + j];
            el[t] = e;
            sl[t] = (e >= 0) ? s_obj[e] : -1e30f;
        }
        __syncthreads();
        float m = -1e30f;
        for (int i = 0; i < 64; ++i) m = fmaxf(m, sl[i]);
        __syncthreads();
        if (t < 64) sl[t] = (el[t] >= 0) ? expf(sl[t] - m) : 0.f;
        __syncthreads();
        float sum = 0.f;
        for (int i = 0; i < 64; ++i) sum += sl[i];
        const float inv = 1.f / sum;
        float4 acc = make_float4(0.f, 0.f, 0.f, 0.f);
        for (int i = 0; i < 64; ++i) {
            const int e = el[i];
            if (e >= 0) {
                const float w = sl[i] * inv;
                const float4 v = relj4[(size_t)e * 256 + t];
                acc.x += w * v.x; acc.y += w * v.y; acc.z += w * v.z; acc.w += w * v.w;
            }
        }
        reinterpret_cast<float4*>(ctx2)[(size_t)j * 256 + t] = acc;
    }
}

// =====================================================================
extern "C" void kernel_launch(void* const* d_in, const int* in_sizes, int n_in,
                              void* d_out, int out_size, void* d_ws, size_t ws_size,
                              hipStream_t stream)
{
    const float* visual   = (const float*)d_in[0];
    const float* relvis   = (const float*)d_in[1];
    const int*   conn     = (const int*)d_in[2];
    const int*   edge_idx = (const int*)d_in[4];
    const float* W_sub    = (const float*)d_in[5];
    const float* W_obj    = (const float*)d_in[6];
    const float* W_r2s    = (const float*)d_in[7];
    const float* W_r2o    = (const float*)d_in[8];
    const float* W_joint  = (const float*)d_in[9];
    const float* W_ctx    = (const float*)d_in[10];
    const float* W_relu   = (const float*)d_in[11];  // (D,3D): Ws|Wo|Wr
    const float* W_relj   = (const float*)d_in[12];
    const float* W_relc   = (const float*)d_in[13];
    const float* W_node   = (const float*)d_in[14];
    const float* b_node   = (const float*)d_in[15];
    const float* W_factor = (const float*)d_in[16];
    (void)in_sizes; (void)n_in; (void)out_size; (void)ws_size;

    float* ws = (float*)d_ws;
    size_t off = 0;
    auto allocF = [&](size_t n) { float* p = ws + off; off += n; return p; };
    auto allocU = [&](size_t n) { return (unsigned short*)allocF((n + 1) / 2); };

    float* part  = allocF((size_t)14 * 1024 * 1024);  // 56 MB partials
    float* asqw  = allocF((size_t)4 * 64 * 1024);     // a_s | a_o | qW_s | qW_o
    float* relj  = allocF((size_t)kE * kD);
    float* R0    = allocF((size_t)kE * kD);
    float* rcA   = allocF((size_t)kE * kD);
    float* rcB   = allocF((size_t)kE * kD);
    float* G0    = allocF((size_t)kN * kD);
    float* vctxA = allocF((size_t)kN * kD);
    float* vctxB = allocF((size_t)kN * kD);
    float* ctx1  = allocF((size_t)kN * kD);
    float* ctx2  = allocF((size_t)kN * kD);
    float* s_sbj = allocF(kE);
    float* s_obj = allocF(kE);
    unsigned short* vj_b = allocU((size_t)kN * kD);
    unsigned short* rj_b = allocU((size_t)kE * kD);
    unsigned short* Wb_ctx    = allocU((size_t)kD * 3 * kD);
    unsigned short* Wb_relu   = allocU((size_t)kD * 3 * kD);
    unsigned short* Wb_relc   = allocU((size_t)kD * 2 * kD);
    unsigned short* Wb_node   = allocU((size_t)kD * 2 * kD);
    unsigned short* Wb_factor = allocU((size_t)kD * 2 * kD);
    unsigned short* WsubT = allocU((size_t)kD * kD);
    unsigned short* WobjT = allocU((size_t)kD * kD);
    unsigned short* Wr2sT = allocU((size_t)kD * kD);
    unsigned short* Wr2oT = allocU((size_t)kD * kD);
    unsigned short* Wc_s  = allocU((size_t)kD * kD);
    unsigned short* Wc_o  = allocU((size_t)kD * kD);
    unsigned short* WrtRel  = allocU((size_t)kD * kD);      // W1+W4
    unsigned short* WeffRel = allocU((size_t)kD * 2 * kD);  // [W2-W4 | W3]
    unsigned short* UrtVj   = allocU((size_t)kD * kD);      // U1-U4
    unsigned short* UeffVj  = allocU((size_t)kD * 2 * kD);  // [U2+U4 | U3]

    auto bfA = [](const unsigned short* p) {
        ASrc a; a.bf = p; a.f0 = a.f1 = a.f2 = nullptr; a.mode = 0; return a;
    };
    auto segA = [](const float* f0, const float* f1, const float* f2) {
        ASrc a; a.bf = nullptr; a.f0 = f0; a.f1 = f1; a.f2 = f2; a.mode = 1; return a;
    };
    auto prodA = [](const float* c, const float* x) {  // [c | c*x]
        ASrc a; a.bf = nullptr; a.f0 = c; a.f1 = x; a.f2 = nullptr; a.mode = 2; return a;
    };

    // ---- job-list launch helpers ----
    GJobs G; RJobs R;
    int gn = 0, gt = 0, rn = 0, rt = 0;
    auto gReset = [&]() { gn = 0; gt = 0; };
    auto gAdd = [&](ASrc a, const unsigned short* W, int ldw, float* P, int M, int K, int KS) {
        G.j[gn].a = a; G.j[gn].W = W; G.j[gn].ldw = ldw; G.j[gn].P = P;
        G.j[gn].M = M; G.j[gn].K = K; G.j[gn].KS = KS;
        G.t0[gn] = gt; gt += KS * (M >> 6) * 8; ++gn;
    };
    auto gLaunch = [&]() {
        G.nj = gn; G.t0[gn] = gt;
        hipLaunchKernelGGL(k_gemm, dim3(gt), dim3(256), 0, stream, G);
        gReset();
    };
    auto rReset = [&]() { rn = 0; rt = 0; };
    auto rAdd = [&](const float* P, int MO4, int KS, float* Cf, unsigned short* Cb,
                    const float* addf, const float* bias, int gather) {
        R.j[rn].P = P; R.j[rn].MO4 = MO4; R.j[rn].KS = KS; R.j[rn].Cf = Cf; R.j[rn].Cb = Cb;
        R.j[rn].addf = addf; R.j[rn].bias = bias; R.j[rn].gather = gather;
        R.t0[rn] = rt; rt += (MO4 + 255) / 256; ++rn;
    };
    auto rLaunch = [&](const int* eidx, const float* gP, int gKS) {
        R.nj = rn; R.t0[rn] = rt; R.eidx = eidx; R.gP = gP; R.gKS = gKS;
        hipLaunchKernelGGL(k_reduce, dim3(rt), dim3(256), 0, stream, R);
        rReset();
    };

    // ---- setup ----
    {
        ConvBatch cb;
        const float* srcs[5] = {W_ctx, W_relu, W_relc, W_node, W_factor};
        unsigned short* dsts[5] = {Wb_ctx, Wb_relu, Wb_relc, Wb_node, Wb_factor};
        const int nel[5] = {3 * 1024 * 1024, 3 * 1024 * 1024, 2 * 1024 * 1024,
                            2 * 1024 * 1024, 2 * 1024 * 1024};
        int cum = 0;
        for (int k = 0; k < 5; ++k) { cb.s[k] = srcs[k]; cb.d[k] = dsts[k]; cb.beg8[k] = cum; cum += nel[k] / 8; }
        cb.total8 = cum;
        hipLaunchKernelGGL(k_f2b_batch, dim3((cum + 255) / 256), dim3(256), 0, stream, cb);
    }
    {
        T4 t4;
        t4.s[0] = W_sub; t4.d[0] = WsubT;
        t4.s[1] = W_obj; t4.d[1] = WobjT;
        t4.s[2] = W_r2s; t4.d[2] = Wr2sT;
        t4.s[3] = W_r2o; t4.d[3] = Wr2oT;
        hipLaunchKernelGGL(k_transpose, dim3(16, 16, 4), dim3(256), 0, stream, t4);
    }
    hipLaunchKernelGGL(k_buildW, dim3(1024, 1, 2), dim3(256), 0, stream,
                       W_relj, W_joint, WrtRel, WeffRel, UrtVj, UeffVj);

    const size_t M1 = 1024 * 1024;
    // S4: Wc_s, Wc_o, R0, G0 in one launch
    gAdd(bfA(Wr2sT), WsubT, 1024, part, 1024, 1024, 4);
    gAdd(bfA(Wr2oT), WobjT, 1024, part + 4 * M1, 1024, 1024, 4);
    gAdd(segA(relvis, nullptr, nullptr), WrtRel, 1024, part + 8 * M1, 1024, 1024, 4);
    gAdd(segA(visual, nullptr, nullptr), UrtVj, 1024, part + 12 * M1, 64, 1024, 4);
    gLaunch();
    // S5
    rAdd(part, 262144, 4, nullptr, Wc_s, nullptr, nullptr, 0);
    rAdd(part + 4 * M1, 262144, 4, nullptr, Wc_o, nullptr, nullptr, 0);
    rAdd(part + 8 * M1, 262144, 4, R0, nullptr, nullptr, nullptr, 0);
    rAdd(part + 12 * M1, 16384, 4, G0, nullptr, nullptr, nullptr, 0);
    rLaunch(nullptr, nullptr, 0);

    // ---- T iterations ----
    for (int t = 0; t < kT; ++t) {
        const float* vcur   = (t == 0) ? visual : vctxA;
        float*       vnext  = (t == 0) ? vctxA : vctxB;
        const float* rccur  = (t == 0) ? relvis : rcA;
        float*       rcnext = (t == 0) ? rcA : rcB;

        // L1: vj-partials, rj-partials
        gAdd(prodA(vcur, visual), UeffVj, 2048, part, 64, 2048, 8);
        gAdd(prodA(rccur, relvis), WeffRel, 2048, part + M1, 1024, 2048, 8);
        gLaunch();
        // L2: vj = G0 + sum -> bf16 ; rj = R0 + sum -> bf16
        rAdd(part, 16384, 8, nullptr, vj_b, G0, nullptr, 0);
        rAdd(part + M1, 262144, 8, nullptr, rj_b, R0, nullptr, 0);
        rLaunch(nullptr, nullptr, 0);

        // L3: asqw (4 jobs, KS=2) + relj (KS=8)
        gAdd(bfA(vj_b), Wb_relu,        3072, part,          64, 1024, 2);  // a_s
        gAdd(bfA(vj_b), Wb_relu + 1024, 3072, part + 131072, 64, 1024, 2);  // a_o
        gAdd(bfA(vj_b), Wc_s,           1024, part + 262144, 64, 1024, 2);  // qW_s
        gAdd(bfA(vj_b), Wc_o,           1024, part + 393216, 64, 1024, 2);  // qW_o
        gAdd(bfA(rj_b), Wb_relu + 2048, 3072, part + M1,   1024, 1024, 8);  // relj
        gLaunch();
        // L4: asqw sums (f32) + relj (= sum + gather a_s/a_o from asqw partials)
        rAdd(part,          16384, 2, asqw,           nullptr, nullptr, nullptr, 0);
        rAdd(part + 131072, 16384, 2, asqw + 65536,   nullptr, nullptr, nullptr, 0);
        rAdd(part + 262144, 16384, 2, asqw + 131072,  nullptr, nullptr, nullptr, 0);
        rAdd(part + 393216, 16384, 2, asqw + 196608,  nullptr, nullptr, nullptr, 0);
        rAdd(part + M1,    262144, 8, relj,           nullptr, nullptr, nullptr, 1);
        rLaunch(edge_idx, part, 2);

        // L5/L6: scores + softmax/aggregate
        hipLaunchKernelGGL(k_scores, dim3(kE), dim3(256), 0, stream,
                           asqw + 131072, asqw + 196608, relj, edge_idx, s_sbj, s_obj);
        hipLaunchKernelGGL(k_ctx12, dim3(128), dim3(256), 0, stream,
                           relj, s_sbj, s_obj, conn, ctx1, ctx2);

        // L7: vctx' + rc'
        gAdd(segA(vcur, ctx1, ctx2), Wb_ctx, 3072, part, 64, 3072, 8);
        gAdd(segA(rccur, relj, nullptr), Wb_relc, 2048, part + M1, 1024, 2048, 8);
        gLaunch();
        // L8
        rAdd(part, 16384, 8, vnext, nullptr, nullptr, nullptr, 0);
        rAdd(part + M1, 262144, 8, rcnext, nullptr, nullptr, nullptr, 0);
        rLaunch(nullptr, nullptr, 0);
    }

    float* rel_out = (float*)d_out;
    float* v_out   = (float*)d_out + (size_t)kE * kD;
    // F1: rel_out + v_out GEMMs
    gAdd(segA(relvis, rcB, nullptr), Wb_factor, 2048, part + M1, 1024, 2048, 8);
    gAdd(segA(visual, vctxB, nullptr), Wb_node, 2048, part, 64, 2048, 8);
    gLaunch();
    // F2
    rAdd(part + M1, 262144, 8, rel_out, nullptr, nullptr, nullptr, 0);
    rAdd(part, 16384, 8, v_out, nullptr, nullptr, b_node, 0);
    rLaunch(nullptr, nullptr, 0);
}

// Round 7
// 222.386 us; speedup vs baseline: 1.9443x; 1.6252x over previous
//
#include <hip/hip_runtime.h>

// ---- problem constants ----
static constexpr int kN = 64;    // nodes
static constexpr int kD = 1024;  // feature dim
static constexpr int kE = 1024;  // edges (16 per row, row-major by (i,j))
static constexpr int kT = 2;     // iterations

typedef short  bf16x8 __attribute__((ext_vector_type(8)));
typedef float  f32x4  __attribute__((ext_vector_type(4)));
typedef unsigned short us8 __attribute__((ext_vector_type(8)));
typedef unsigned short us4 __attribute__((ext_vector_type(4)));

__device__ __forceinline__ unsigned short f2b(float f) {
    unsigned int u = __builtin_bit_cast(unsigned int, f);
    u += 0x7FFFu + ((u >> 16) & 1u);          // RNE
    return (unsigned short)(u >> 16);
}
__device__ __forceinline__ float b2f(unsigned short u) {
    unsigned int x = ((unsigned int)u) << 16;
    return __builtin_bit_cast(float, x);
}
__device__ __forceinline__ bf16x8 cvt8(float4 a, float4 b) {
    us8 o;
    o[0] = f2b(a.x); o[1] = f2b(a.y); o[2] = f2b(a.z); o[3] = f2b(a.w);
    o[4] = f2b(b.x); o[5] = f2b(b.y); o[6] = f2b(b.z); o[7] = f2b(b.w);
    return __builtin_bit_cast(bf16x8, o);
}

// A-operand source, ALL bf16 [row][1024] segments:
// mode 1: concat of segments s0|s1|s2 ; mode 2: [s0 | s0*s1]
struct ASrc { const unsigned short* s0; const unsigned short* s1; const unsigned short* s2; int mode; };

__device__ __forceinline__ bf16x8 loadA8(const ASrc& s, int row, int kg) {
    const int seg = kg >> 10, k = kg & 1023;
    const size_t ro = (size_t)row * 1024 + k;
    if (s.mode == 1) {
        const unsigned short* p = (seg == 0) ? s.s0 : (seg == 1 ? s.s1 : s.s2);
        return *(const bf16x8*)(p + ro);
    }
    const bf16x8 a = *(const bf16x8*)(s.s0 + ro);
    if (seg == 0) return a;
    const bf16x8 b = *(const bf16x8*)(s.s1 + ro);
    const us8 ua = __builtin_bit_cast(us8, a), ub = __builtin_bit_cast(us8, b);
    us8 o;
#pragma unroll
    for (int q = 0; q < 8; ++q) o[q] = f2b(b2f(ua[q]) * b2f(ub[q]));
    return __builtin_bit_cast(bf16x8, o);
}

// =====================================================================
// Job-list MFMA GEMM. Tile 64 rows x 128 cols, 4 waves (2x2), BK=64.
// Block decode: rt fastest (rowTiles mult of 8 -> rt%8 == XCD for all ct,z:
// A-stripe stays in one XCD's L2). pbf: bf16 partials via LDS-coalesced
// epilogue; else f32 direct store (skinny jobs).
// =====================================================================
struct GJob { ASrc a; const unsigned short* W; int ldw; void* P; int M; int K; int KS; int pbf; };
struct GJobs { GJob j[5]; int t0[6]; int nj; };

__global__ __launch_bounds__(256)
void k_gemm(GJobs G)
{
    __shared__ unsigned short lds[12288];   // As[64][64] | Bs[128][64]; epilogue Cs[64][132]
    const int flat = blockIdx.x;
    int ji = 0;
    while (ji + 1 < G.nj && flat >= G.t0[ji + 1]) ++ji;
    const GJob J = G.j[ji];
    const int local = flat - G.t0[ji];
    const int rowTiles = J.M >> 6;
    const int rt = local & (rowTiles - 1);           // fastest -> XCD affinity
    const int rest = local / rowTiles;
    const int ct = rest & 7, z = rest >> 3;
    const int rowBase = rt * 64, colBase = ct * 128;
    const int kchunk = J.K / J.KS, kbeg = z * kchunk, kend = kbeg + kchunk;

    const int tid = threadIdx.x, lane = tid & 63, wid = tid >> 6;
    const int sr = tid >> 3, sc8 = tid & 7;
    const int wc8 = (sc8 ^ (sr & 7)) * 8;

    bf16x8 ra[2], rb[4];
    auto stage = [&](int kt) {
#pragma unroll
        for (int h = 0; h < 2; ++h)
            ra[h] = loadA8(J.a, rowBase + sr + 32 * h, kt + sc8 * 8);
#pragma unroll
        for (int h = 0; h < 4; ++h)
            rb[h] = *(const bf16x8*)(J.W + (size_t)(colBase + sr + 32 * h) * J.ldw + kt + sc8 * 8);
    };

    f32x4 acc[2][4] = {};
    const int wr = wid >> 1, wc = wid & 1;
    const int l15 = lane & 15, l4 = lane >> 4;

    stage(kbeg);
    for (int kt = kbeg; kt < kend; kt += 64) {
        __syncthreads();
#pragma unroll
        for (int h = 0; h < 2; ++h)
            *(bf16x8*)&lds[(sr + 32 * h) * 64 + wc8] = ra[h];
#pragma unroll
        for (int h = 0; h < 4; ++h)
            *(bf16x8*)&lds[4096 + (sr + 32 * h) * 64 + wc8] = rb[h];
        __syncthreads();
        if (kt + 64 < kend) stage(kt + 64);
#pragma unroll
        for (int kk = 0; kk < 2; ++kk) {
            const int c8 = kk * 4 + l4;
            bf16x8 af[2], bv[4];
#pragma unroll
            for (int m = 0; m < 2; ++m) {
                const int ar = wr * 32 + m * 16 + l15;
                af[m] = *(const bf16x8*)&lds[ar * 64 + (c8 ^ (ar & 7)) * 8];
            }
#pragma unroll
            for (int n = 0; n < 4; ++n) {
                const int br = wc * 64 + n * 16 + l15;
                bv[n] = *(const bf16x8*)&lds[4096 + br * 64 + (c8 ^ (br & 7)) * 8];
            }
#pragma unroll
            for (int m = 0; m < 2; ++m)
#pragma unroll
                for (int n = 0; n < 4; ++n)
                    acc[m][n] = __builtin_amdgcn_mfma_f32_16x16x32_bf16(af[m], bv[n], acc[m][n], 0, 0, 0);
        }
    }

    if (J.pbf) {
        // bf16 partial, LDS-coalesced: Cs[64][132]
        __syncthreads();
#pragma unroll
        for (int m = 0; m < 2; ++m)
#pragma unroll
            for (int n = 0; n < 4; ++n)
#pragma unroll
                for (int r = 0; r < 4; ++r)
                    lds[(wr * 32 + m * 16 + l4 * 4 + r) * 132 + wc * 64 + n * 16 + l15] =
                        f2b(acc[m][n][r]);
        __syncthreads();
        unsigned short* Pb = (unsigned short*)J.P + (size_t)z * J.M * 1024;
#pragma unroll
        for (int c = tid; c < 1024; c += 256) {
            const int row = c >> 4, ch = c & 15;
            *(bf16x8*)(Pb + (size_t)(rowBase + row) * 1024 + colBase + ch * 8) =
                *(const bf16x8*)&lds[row * 132 + ch * 8];
        }
    } else {
        float* base = (float*)J.P + (size_t)z * J.M * 1024;
#pragma unroll
        for (int m = 0; m < 2; ++m) {
            const int row = rowBase + wr * 32 + m * 16 + l4 * 4;
#pragma unroll
            for (int n = 0; n < 4; ++n) {
                const int col = colBase + wc * 64 + n * 16 + l15;
#pragma unroll
                for (int r = 0; r < 4; ++r)
                    base[(size_t)(row + r) * 1024 + col] = acc[m][n][r];
            }
        }
    }
}

// =====================================================================
// Job-list split-K reduce, 8-elem granularity.
// out = sum_z P[z] (+addb bf16) (+bias) (+gather a_s/a_o from f32 partials)
// =====================================================================
struct RJob { const void* P; int MO8; int KS; int pbf; float* Cf; unsigned short* Cb;
              const unsigned short* addb; const float* bias; int gather; };
struct RJobs { RJob j[6]; int t0[7]; int nj; const int* eidx; const float* gP; int gKS; };

__global__ void k_reduce(RJobs R)
{
    const int flat = blockIdx.x;
    int ji = 0;
    while (ji + 1 < R.nj && flat >= R.t0[ji + 1]) ++ji;
    const RJob J = R.j[ji];
    const int i8 = (flat - R.t0[ji]) * 256 + threadIdx.x;
    if (i8 >= J.MO8) return;
    float s[8] = {0.f, 0.f, 0.f, 0.f, 0.f, 0.f, 0.f, 0.f};
    if (J.pbf) {
        const unsigned short* P = (const unsigned short*)J.P;
        for (int z = 0; z < J.KS; ++z) {
            const us8 v = *(const us8*)(P + (size_t)z * J.MO8 * 8 + (size_t)i8 * 8);
#pragma unroll
            for (int q = 0; q < 8; ++q) s[q] += b2f(v[q]);
        }
    } else {
        const float* P = (const float*)J.P;
        for (int z = 0; z < J.KS; ++z) {
            const float* p = P + (size_t)z * J.MO8 * 8 + (size_t)i8 * 8;
            const float4 v0 = *(const float4*)p;
            const float4 v1 = *(const float4*)(p + 4);
            s[0] += v0.x; s[1] += v0.y; s[2] += v0.z; s[3] += v0.w;
            s[4] += v1.x; s[5] += v1.y; s[6] += v1.z; s[7] += v1.w;
        }
    }
    if (J.addb) {
        const us8 v = *(const us8*)(J.addb + (size_t)i8 * 8);
#pragma unroll
        for (int q = 0; q < 8; ++q) s[q] += b2f(v[q]);
    }
    if (J.gather) {
        const int e = i8 >> 7, c8 = i8 & 127;
        const int idx = R.eidx[e];
        const float* as_ = R.gP + (size_t)(idx >> 6) * 1024 + c8 * 8;
        const float* ao_ = R.gP + 131072 + (size_t)(idx & 63) * 1024 + c8 * 8;
        for (int z = 0; z < R.gKS; ++z) {
#pragma unroll
            for (int q = 0; q < 8; ++q)
                s[q] += as_[(size_t)z * 65536 + q] + ao_[(size_t)z * 65536 + q];
        }
    }
    if (J.bias) {
        const int c8 = i8 & 127;
#pragma unroll
        for (int q = 0; q < 8; ++q) s[q] += J.bias[c8 * 8 + q];
    }
    if (J.Cf) {
        *(float4*)(J.Cf + (size_t)i8 * 8)     = make_float4(s[0], s[1], s[2], s[3]);
        *(float4*)(J.Cf + (size_t)i8 * 8 + 4) = make_float4(s[4], s[5], s[6], s[7]);
    }
    if (J.Cb) {
        us8 o;
#pragma unroll
        for (int q = 0; q < 8; ++q) o[q] = f2b(s[q]);
        *(us8*)(J.Cb + (size_t)i8 * 8) = o;
    }
}

// batched f32 -> bf16 conversion (7 matrices), one launch
struct ConvBatch { const float* s[7]; unsigned short* d[7]; int beg8[7]; int total8; };
__global__ void k_f2b_batch(ConvBatch cb)
{
    int i = blockIdx.x * blockDim.x + threadIdx.x;
    if (i >= cb.total8) return;
    int k = 0;
    while (k < 6 && i >= cb.beg8[k + 1]) ++k;
    const int j = i - cb.beg8[k];
    const float4 v0 = reinterpret_cast<const float4*>(cb.s[k])[2 * j];
    const float4 v1 = reinterpret_cast<const float4*>(cb.s[k])[2 * j + 1];
    const bf16x8 o = cvt8(v0, v1);
    *(bf16x8*)(cb.d[k] + (size_t)j * 8) = o;
}

// transpose 4 f32 [1024][1024] matrices into bf16 (dst[k][o] = src[o][k])
struct T4 { const float* s[4]; unsigned short* d[4]; };
__global__ __launch_bounds__(256)
void k_transpose(T4 t4)
{
    __shared__ float tile[64][65];
    const float* __restrict__ src = t4.s[blockIdx.z];
    unsigned short* __restrict__ dst = t4.d[blockIdx.z];
    const int bx = blockIdx.x * 64, by = blockIdx.y * 64;
    const int c = threadIdx.x & 63, r0 = threadIdx.x >> 6;
#pragma unroll
    for (int h = 0; h < 16; ++h) {
        const int r = r0 * 16 + h;
        tile[r][c] = src[(size_t)(by + r) * 1024 + bx + c];
    }
    __syncthreads();
#pragma unroll
    for (int h = 0; h < 16; ++h) {
        const int kk = r0 * 16 + h;
        dst[(size_t)(bx + kk) * 1024 + by + c] = f2b(tile[c][kk]);
    }
}

// build folded joint weights from W (1024 x 4096, slices W1|W2|W3|W4):
// z=0 (rel, s=+1):  rt = W1+W4,  eff = [W2-W4 | W3]
// z=1 (vj,  s=-1):  rt = W1-W4,  eff = [W2+W4 | W3]
__global__ __launch_bounds__(256)
void k_buildW(const float* __restrict__ Wrel, const float* __restrict__ Wjnt,
              unsigned short* __restrict__ WrtRel, unsigned short* __restrict__ WeffRel,
              unsigned short* __restrict__ UrtVj, unsigned short* __restrict__ UeffVj)
{
    const int idx = blockIdx.x * 256 + threadIdx.x;     // [0, 1024*256)
    const int o = idx >> 8, j = (idx & 255) * 4;
    const float* W = blockIdx.z ? Wjnt : Wrel;
    const float sgn = blockIdx.z ? -1.f : 1.f;
    unsigned short* rt = blockIdx.z ? UrtVj : WrtRel;
    unsigned short* ef = blockIdx.z ? UeffVj : WeffRel;
    const float4 w1 = *(const float4*)(W + (size_t)o * 4096 + j);
    const float4 w2 = *(const float4*)(W + (size_t)o * 4096 + 1024 + j);
    const float4 w3 = *(const float4*)(W + (size_t)o * 4096 + 2048 + j);
    const float4 w4 = *(const float4*)(W + (size_t)o * 4096 + 3072 + j);
    us4 t;
    t.x = f2b(w1.x + sgn * w4.x); t.y = f2b(w1.y + sgn * w4.y);
    t.z = f2b(w1.z + sgn * w4.z); t.w = f2b(w1.w + sgn * w4.w);
    *(us4*)(rt + (size_t)o * 1024 + j) = t;
    t.x = f2b(w2.x - sgn * w4.x); t.y = f2b(w2.y - sgn * w4.y);
    t.z = f2b(w2.z - sgn * w4.z); t.w = f2b(w2.w - sgn * w4.w);
    *(us4*)(ef + (size_t)o * 2048 + j) = t;
    t.x = f2b(w3.x); t.y = f2b(w3.y); t.z = f2b(w3.z); t.w = f2b(w3.w);
    *(us4*)(ef + (size_t)o * 2048 + 1024 + j) = t;
}

// s_sbj[e] = <qW_s[i_e], relj[e]>/32 ; s_obj[e] = <qW_o[j_e], relj[e]>/32
__global__ __launch_bounds__(256)
void k_scores(const float* __restrict__ qws, const float* __restrict__ qwo,
              const float* __restrict__ relj, const int* __restrict__ eidx,
              float* __restrict__ s_sbj, float* __restrict__ s_obj)
{
    const int e = blockIdx.x, t = threadIdx.x;
    const int idx = eidx[e];
    const int i = idx >> 6, j = idx & 63;
    const float4 r = reinterpret_cast<const float4*>(relj)[(size_t)e * 256 + t];
    const float4 a = reinterpret_cast<const float4*>(qws)[(size_t)i * 256 + t];
    const float4 b = reinterpret_cast<const float4*>(qwo)[(size_t)j * 256 + t];
    float vs = a.x * r.x + a.y * r.y + a.z * r.z + a.w * r.w;
    float vo = b.x * r.x + b.y * r.y + b.z * r.z + b.w * r.w;
    for (int off = 32; off; off >>= 1) {
        vs += __shfl_down(vs, off);
        vo += __shfl_down(vo, off);
    }
    __shared__ float ss[4], so[4];
    const int w = t >> 6, lane = t & 63;
    if (lane == 0) { ss[w] = vs; so[w] = vo; }
    __syncthreads();
    if (t == 0) {
        s_sbj[e] = (ss[0] + ss[1] + ss[2] + ss[3]) * 0.03125f;
        s_obj[e] = (so[0] + so[1] + so[2] + so[3]) * 0.03125f;
    }
}

// fused softmax + weighted aggregation -> bf16 ctx outputs
__global__ __launch_bounds__(256)
void k_ctx12(const float* __restrict__ relj, const float* __restrict__ s_sbj,
             const float* __restrict__ s_obj, const int* __restrict__ conn,
             unsigned short* __restrict__ ctx1b, unsigned short* __restrict__ ctx2b)
{
    const int bid = blockIdx.x, t = threadIdx.x;
    const float4* relj4 = reinterpret_cast<const float4*>(relj);
    float4 acc = make_float4(0.f, 0.f, 0.f, 0.f);
    if (bid < 64) {
        const int i = bid;
        float sv[16];
        float m = -1e30f;
#pragma unroll
        for (int q = 0; q < 16; ++q) { sv[q] = s_sbj[i * 16 + q]; m = fmaxf(m, sv[q]); }
        float sum = 0.f;
#pragma unroll
        for (int q = 0; q < 16; ++q) { sv[q] = expf(sv[q] - m); sum += sv[q]; }
        const float inv = 1.f / sum;
#pragma unroll
        for (int q = 0; q < 16; ++q) {
            const float w = sv[q] * inv;
            const float4 v = relj4[(size_t)(i * 16 + q) * 256 + t];
            acc.x += w * v.x; acc.y += w * v.y; acc.z += w * v.z; acc.w += w * v.w;
        }
        us4 o; o.x = f2b(acc.x); o.y = f2b(acc.y); o.z = f2b(acc.z); o.w = f2b(acc.w);
        *(us4*)(ctx1b + (size_t)bid * 1024 + t * 4) = o;
    } else {
        const int j = bid - 64;
        __shared__ float sl[64];
        __shared__ int el[64];
        if (t < 64) {
            const int e = conn[t * kN + j];
            el[t] = e;
            sl[t] = (e >= 0) ? s_obj[e] : -1e30f;
        }
        __syncthreads();
        float m = -1e30f;
        for (int i = 0; i < 64; ++i) m = fmaxf(m, sl[i]);
        __syncthreads();
        if (t < 64) sl[t] = (el[t] >= 0) ? expf(sl[t] - m) : 0.f;
        __syncthreads();
        float sum = 0.f;
        for (int i = 0; i < 64; ++i) sum += sl[i];
        const float inv = 1.f / sum;
        for (int i = 0; i < 64; ++i) {
            const int e = el[i];
            if (e >= 0) {
                const float w = sl[i] * inv;
                const float4 v = relj4[(size_t)e * 256 + t];
                acc.x += w * v.x; acc.y += w * v.y; acc.z += w * v.z; acc.w += w * v.w;
            }
        }
        us4 o; o.x = f2b(acc.x); o.y = f2b(acc.y); o.z = f2b(acc.z); o.w = f2b(acc.w);
        *(us4*)(ctx2b + (size_t)j * 1024 + t * 4) = o;
    }
}

// =====================================================================
extern "C" void kernel_launch(void* const* d_in, const int* in_sizes, int n_in,
                              void* d_out, int out_size, void* d_ws, size_t ws_size,
                              hipStream_t stream)
{
    const float* visual   = (const float*)d_in[0];
    const float* relvis   = (const float*)d_in[1];
    const int*   conn     = (const int*)d_in[2];
    const int*   edge_idx = (const int*)d_in[4];
    const float* W_sub    = (const float*)d_in[5];
    const float* W_obj    = (const float*)d_in[6];
    const float* W_r2s    = (const float*)d_in[7];
    const float* W_r2o    = (const float*)d_in[8];
    const float* W_joint  = (const float*)d_in[9];
    const float* W_ctx    = (const float*)d_in[10];
    const float* W_relu   = (const float*)d_in[11];  // (D,3D): Ws|Wo|Wr
    const float* W_relj   = (const float*)d_in[12];
    const float* W_relc   = (const float*)d_in[13];
    const float* W_node   = (const float*)d_in[14];
    const float* b_node   = (const float*)d_in[15];
    const float* W_factor = (const float*)d_in[16];
    (void)in_sizes; (void)n_in; (void)out_size; (void)ws_size;

    float* ws = (float*)d_ws;
    size_t off = 0;
    auto allocF = [&](size_t n) { float* p = ws + off; off += n; return p; };
    auto allocU = [&](size_t n) { return (unsigned short*)allocF((n + 1) / 2); };

    float* partF = allocF((size_t)1024 * 1024);          // f32 partials (skinny)
    unsigned short* partB = allocU((size_t)16 * 1024 * 1024);  // bf16 partials
    float* asqw  = allocF((size_t)4 * 64 * 1024);        // a_s | a_o | qW_s | qW_o (f32)
    float* relj  = allocF((size_t)kE * kD);
    float* s_sbj = allocF(kE);
    float* s_obj = allocF(kE);
    unsigned short* relvis_b = allocU((size_t)kE * kD);
    unsigned short* visual_b = allocU((size_t)kN * kD);
    unsigned short* vj_b   = allocU((size_t)kN * kD);
    unsigned short* rj_b   = allocU((size_t)kE * kD);
    unsigned short* relj_b = allocU((size_t)kE * kD);
    unsigned short* rc_bA  = allocU((size_t)kE * kD);
    unsigned short* rc_bB  = allocU((size_t)kE * kD);
    unsigned short* vctx_bA = allocU((size_t)kN * kD);
    unsigned short* vctx_bB = allocU((size_t)kN * kD);
    unsigned short* ctx1_b = allocU((size_t)kN * kD);
    unsigned short* ctx2_b = allocU((size_t)kN * kD);
    unsigned short* R0_b = allocU((size_t)kE * kD);
    unsigned short* G0_b = allocU((size_t)kN * kD);
    unsigned short* Wb_ctx    = allocU((size_t)kD * 3 * kD);
    unsigned short* Wb_relu   = allocU((size_t)kD * 3 * kD);
    unsigned short* Wb_relc   = allocU((size_t)kD * 2 * kD);
    unsigned short* Wb_node   = allocU((size_t)kD * 2 * kD);
    unsigned short* Wb_factor = allocU((size_t)kD * 2 * kD);
    unsigned short* WsubT = allocU((size_t)kD * kD);
    unsigned short* WobjT = allocU((size_t)kD * kD);
    unsigned short* Wr2sT = allocU((size_t)kD * kD);
    unsigned short* Wr2oT = allocU((size_t)kD * kD);
    unsigned short* Wc_s  = allocU((size_t)kD * kD);
    unsigned short* Wc_o  = allocU((size_t)kD * kD);
    unsigned short* WrtRel  = allocU((size_t)kD * kD);      // W1+W4
    unsigned short* WeffRel = allocU((size_t)kD * 2 * kD);  // [W2-W4 | W3]
    unsigned short* UrtVj   = allocU((size_t)kD * kD);      // U1-U4
    unsigned short* UeffVj  = allocU((size_t)kD * 2 * kD);  // [U2+U4 | U3]

    auto seg1 = [](const unsigned short* a) {
        ASrc s; s.s0 = a; s.s1 = nullptr; s.s2 = nullptr; s.mode = 1; return s;
    };
    auto seg2 = [](const unsigned short* a, const unsigned short* b) {
        ASrc s; s.s0 = a; s.s1 = b; s.s2 = nullptr; s.mode = 1; return s;
    };
    auto seg3 = [](const unsigned short* a, const unsigned short* b, const unsigned short* c) {
        ASrc s; s.s0 = a; s.s1 = b; s.s2 = c; s.mode = 1; return s;
    };
    auto prodA = [](const unsigned short* c, const unsigned short* x) {  // [c | c*x]
        ASrc s; s.s0 = c; s.s1 = x; s.s2 = nullptr; s.mode = 2; return s;
    };

    // ---- job-list launch helpers ----
    GJobs G; RJobs R;
    int gn = 0, gt = 0, rn = 0, rtt = 0;
    auto gAdd = [&](ASrc a, const unsigned short* W, int ldw, void* P, int M, int K, int KS, int pbf) {
        G.j[gn].a = a; G.j[gn].W = W; G.j[gn].ldw = ldw; G.j[gn].P = P;
        G.j[gn].M = M; G.j[gn].K = K; G.j[gn].KS = KS; G.j[gn].pbf = pbf;
        G.t0[gn] = gt; gt += KS * (M >> 6) * 8; ++gn;
    };
    auto gLaunch = [&]() {
        G.nj = gn; G.t0[gn] = gt;
        hipLaunchKernelGGL(k_gemm, dim3(gt), dim3(256), 0, stream, G);
        gn = 0; gt = 0;
    };
    auto rAdd = [&](const void* P, int MO8, int KS, int pbf, float* Cf, unsigned short* Cb,
                    const unsigned short* addb, const float* bias, int gather) {
        R.j[rn].P = P; R.j[rn].MO8 = MO8; R.j[rn].KS = KS; R.j[rn].pbf = pbf;
        R.j[rn].Cf = Cf; R.j[rn].Cb = Cb; R.j[rn].addb = addb; R.j[rn].bias = bias;
        R.j[rn].gather = gather;
        R.t0[rn] = rtt; rtt += (MO8 + 255) / 256; ++rn;
    };
    auto rLaunch = [&](const int* eidx, const float* gP, int gKS) {
        R.nj = rn; R.t0[rn] = rtt; R.eidx = eidx; R.gP = gP; R.gKS = gKS;
        hipLaunchKernelGGL(k_reduce, dim3(rtt), dim3(256), 0, stream, R);
        rn = 0; rtt = 0;
    };

    // ---- setup ----
    {
        ConvBatch cb;
        const float* srcs[7] = {W_ctx, W_relu, W_relc, W_node, W_factor, relvis, visual};
        unsigned short* dsts[7] = {Wb_ctx, Wb_relu, Wb_relc, Wb_node, Wb_factor, relvis_b, visual_b};
        const int nel[7] = {3 * 1024 * 1024, 3 * 1024 * 1024, 2 * 1024 * 1024,
                            2 * 1024 * 1024, 2 * 1024 * 1024, 1024 * 1024, 64 * 1024};
        int cum = 0;
        for (int k = 0; k < 7; ++k) { cb.s[k] = srcs[k]; cb.d[k] = dsts[k]; cb.beg8[k] = cum; cum += nel[k] / 8; }
        cb.total8 = cum;
        hipLaunchKernelGGL(k_f2b_batch, dim3((cum + 255) / 256), dim3(256), 0, stream, cb);
    }
    {
        T4 t4;
        t4.s[0] = W_sub; t4.d[0] = WsubT;
        t4.s[1] = W_obj; t4.d[1] = WobjT;
        t4.s[2] = W_r2s; t4.d[2] = Wr2sT;
        t4.s[3] = W_r2o; t4.d[3] = Wr2oT;
        hipLaunchKernelGGL(k_transpose, dim3(16, 16, 4), dim3(256), 0, stream, t4);
    }
    hipLaunchKernelGGL(k_buildW, dim3(1024, 1, 2), dim3(256), 0, stream,
                       W_relj, W_joint, WrtRel, WeffRel, UrtVj, UeffVj);

    const size_t PB1 = (size_t)4 * 1024 * 1024;   // bf16 elems per KS=4 M=1024 job
    // S4: Wc_s, Wc_o, R0, G0
    gAdd(seg1(Wr2sT), WsubT, 1024, partB, 1024, 1024, 4, 1);
    gAdd(seg1(Wr2oT), WobjT, 1024, partB + PB1, 1024, 1024, 4, 1);
    gAdd(seg1(relvis_b), WrtRel, 1024, partB + 2 * PB1, 1024, 1024, 4, 1);
    gAdd(seg1(visual_b), UrtVj, 1024, partF, 64, 1024, 4, 0);
    gLaunch();
    // S5
    rAdd(partB, 131072, 4, 1, nullptr, Wc_s, nullptr, nullptr, 0);
    rAdd(partB + PB1, 131072, 4, 1, nullptr, Wc_o, nullptr, nullptr, 0);
    rAdd(partB + 2 * PB1, 131072, 4, 1, nullptr, R0_b, nullptr, nullptr, 0);
    rAdd(partF, 8192, 4, 0, nullptr, G0_b, nullptr, nullptr, 0);
    rLaunch(nullptr, nullptr, 0);

    // ---- T iterations ----
    for (int t = 0; t < kT; ++t) {
        const unsigned short* vcur  = (t == 0) ? visual_b : vctx_bA;
        unsigned short*       vnext = (t == 0) ? vctx_bA : vctx_bB;
        const unsigned short* rccur = (t == 0) ? relvis_b : rc_bA;
        unsigned short*       rcnext = (t == 0) ? rc_bA : rc_bB;

        // L1: vj (f32 partials) + rj (bf16 partials)
        gAdd(prodA(vcur, visual_b), UeffVj, 2048, partF, 64, 2048, 8, 0);
        gAdd(prodA(rccur, relvis_b), WeffRel, 2048, partB, 1024, 2048, 8, 1);
        gLaunch();
        // L2: vj = G0 + sum -> bf16 ; rj = R0 + sum -> bf16
        rAdd(partF, 8192, 8, 0, nullptr, vj_b, G0_b, nullptr, 0);
        rAdd(partB, 131072, 8, 1, nullptr, rj_b, R0_b, nullptr, 0);
        rLaunch(nullptr, nullptr, 0);

        // L3: asqw (4 skinny, f32 KS=2) + relj (bf16 KS=4)
        gAdd(seg1(vj_b), Wb_relu,        3072, partF,          64, 1024, 2, 0);  // a_s
        gAdd(seg1(vj_b), Wb_relu + 1024, 3072, partF + 131072, 64, 1024, 2, 0);  // a_o
        gAdd(seg1(vj_b), Wc_s,           1024, partF + 262144, 64, 1024, 2, 0);  // qW_s
        gAdd(seg1(vj_b), Wc_o,           1024, partF + 393216, 64, 1024, 2, 0);  // qW_o
        gAdd(seg1(rj_b), Wb_relu + 2048, 3072, partB,        1024, 1024, 4, 1);  // relj
        gLaunch();
        // L4: asqw sums + relj (sum + gather a_s/a_o from f32 partials)
        rAdd(partF,          8192, 2, 0, asqw,          nullptr, nullptr, nullptr, 0);
        rAdd(partF + 131072, 8192, 2, 0, asqw + 65536,  nullptr, nullptr, nullptr, 0);
        rAdd(partF + 262144, 8192, 2, 0, asqw + 131072, nullptr, nullptr, nullptr, 0);
        rAdd(partF + 393216, 8192, 2, 0, asqw + 196608, nullptr, nullptr, nullptr, 0);
        rAdd(partB, 131072, 4, 1, relj, relj_b, nullptr, nullptr, 1);
        rLaunch(edge_idx, partF, 2);

        // scores + softmax/aggregate (bf16 ctx out)
        hipLaunchKernelGGL(k_scores, dim3(kE), dim3(256), 0, stream,
                           asqw + 131072, asqw + 196608, relj, edge_idx, s_sbj, s_obj);
        hipLaunchKernelGGL(k_ctx12, dim3(128), dim3(256), 0, stream,
                           relj, s_sbj, s_obj, conn, ctx1_b, ctx2_b);

        // L7: vctx' + rc'
        gAdd(seg3(vcur, ctx1_b, ctx2_b), Wb_ctx, 3072, partF, 64, 3072, 8, 0);
        gAdd(seg2(rccur, relj_b), Wb_relc, 2048, partB, 1024, 2048, 8, 1);
        gLaunch();
        // L8
        rAdd(partF, 8192, 8, 0, nullptr, vnext, nullptr, nullptr, 0);
        rAdd(partB, 131072, 8, 1, nullptr, rcnext, nullptr, nullptr, 0);
        rLaunch(nullptr, nullptr, 0);
    }

    float* rel_out = (float*)d_out;
    float* v_out   = (float*)d_out + (size_t)kE * kD;
    // F1: rel_out (bf16 partials KS=4) + v_out (f32 partials KS=8)
    gAdd(seg2(relvis_b, rc_bB), Wb_factor, 2048, partB, 1024, 2048, 4, 1);
    gAdd(seg2(visual_b, vctx_bB), Wb_node, 2048, partF, 64, 2048, 8, 0);
    gLaunch();
    // F2
    rAdd(partB, 131072, 4, 1, rel_out, nullptr, nullptr, nullptr, 0);
    rAdd(partF, 8192, 8, 0, v_out, nullptr, nullptr, b_node, 0);
    rLaunch(nullptr, nullptr, 0);
}